// Round 4
// baseline (441.088 us; speedup 1.0000x reference)
//
#include <hip/hip_runtime.h>
#include <hip/hip_bf16.h>
#include <math.h>

#define Bc 32
#define Rc 200
#define Nc 200
#define Dc 128
#define Hc 8
#define QKc 16
#define Kc 10
#define BRc (Bc*Rc)
#define GRID 512

typedef __attribute__((ext_vector_type(8))) short short8;
typedef __attribute__((ext_vector_type(4))) float f32x4;
typedef unsigned long long u64;

#define GLOAD_LDS16(g, l) __builtin_amdgcn_global_load_lds( \
    (const __attribute__((address_space(1))) void*)(g), \
    (__attribute__((address_space(3))) void*)(l), 16, 0, 0)

// Device-wide barrier: cumulative target, agent-scope atomics, bounded spin
// (failsafe: if co-residency is ever violated we break instead of hanging).
__device__ __forceinline__ void grid_sync(unsigned* bar, unsigned target)
{
    __syncthreads();
    if (threadIdx.x == 0) {
        __threadfence();
        __hip_atomic_fetch_add(bar, 1u, __ATOMIC_ACQ_REL, __HIP_MEMORY_SCOPE_AGENT);
        unsigned spins = 0;
        while (__hip_atomic_load(bar, __ATOMIC_ACQUIRE, __HIP_MEMORY_SCOPE_AGENT) < target) {
            __builtin_amdgcn_s_sleep(2);
            if (++spins > 10000000u) break;
        }
    }
    __syncthreads();
}

__device__ __forceinline__ void transpose_tile2(float* tile /*32x33 f32*/,
    const float* __restrict__ src, int lds_, __hip_bfloat16* __restrict__ dst,
    int ldd, int k0, int n0, float scale)
{
    int tx = threadIdx.x & 31, ty = threadIdx.x >> 5;  // 32 x 8
    #pragma unroll
    for (int i = ty; i < 32; i += 8)
        tile[i * 33 + tx] = src[(size_t)(k0 + i) * lds_ + n0 + tx];
    __syncthreads();
    #pragma unroll
    for (int i = ty; i < 32; i += 8)
        dst[(size_t)(n0 + i) * ldd + k0 + tx] = __float2bfloat16(tile[tx * 33 + i] * scale);
}

// ---------------------------------------------------------------------------
// One persistent kernel, 5 phases separated by grid_sync.
// Grid 512 x 256 threads; LDS union 76.5 KB -> 2 blocks/CU (all co-resident).
// ---------------------------------------------------------------------------
__global__ __launch_bounds__(256, 2) void mega_kernel(
    const float* __restrict__ W1, const float* __restrict__ W2,
    const float* __restrict__ Wq, const float* __restrict__ Wmhc,
    const float* __restrict__ Wk, const float* __restrict__ Wv,
    const float* __restrict__ bmhc, const float* __restrict__ b1,
    const float* __restrict__ b2, const float* __restrict__ enc,
    const float* __restrict__ dist, const float* __restrict__ maskp,
    const int* __restrict__ cur,
    __hip_bfloat16* __restrict__ W1t, __hip_bfloat16* __restrict__ Wkvt,
    __hip_bfloat16* __restrict__ Wmb, __hip_bfloat16* __restrict__ Wcat,
    float* __restrict__ bq, __hip_bfloat16* __restrict__ encb,
    unsigned* __restrict__ aoff, __hip_bfloat16* __restrict__ hq,
    __hip_bfloat16* __restrict__ q, __hip_bfloat16* __restrict__ kvf,
    __hip_bfloat16* __restrict__ att, __hip_bfloat16* __restrict__ em,
    float* __restrict__ be, u64* __restrict__ maskbits,
    float* __restrict__ out, unsigned* __restrict__ bar)
{
    __shared__ __align__(16) char SMEM[78336];
    int t = threadIdx.x;
    int wave = t >> 6, lane = t & 63;
    int lrow = lane >> 2, cg = lane & 3, ss = (lane >> 3) & 3, gq = (cg - ss) & 3;
    int wm = wave >> 1, wn = wave & 1;
    int rrow = lane & 15, quad = lane >> 4, srd = (rrow >> 1) & 3;
    int strip = (wave & 1) * 32;

    // ======================= P0: prep + kNN ==============================
    for (int j = blockIdx.x; j < 2530; j += GRID) {
        if (j < 800) {
            transpose_tile2((float*)SMEM, W1, 640, W1t, 1280, (j % 40) * 32, (j / 40) * 32, 1.f);
        } else if (j < 816) {
            int id = j - 800;
            transpose_tile2((float*)SMEM, Wk, 128, Wkvt, 128, (id & 3) * 32, (id >> 2) * 32, 1.f);
        } else if (j < 832) {
            int id = j - 816;
            transpose_tile2((float*)SMEM, Wv, 128, Wkvt + 128 * 128, 128, (id & 3) * 32, (id >> 2) * 32, 1.f);
        } else if (j < 848) {
            int e = (j - 832) * 1024 + t * 4;
            #pragma unroll
            for (int jj = 0; jj < 4; ++jj) Wmb[e + jj] = __float2bfloat16(Wmhc[e + jj]);
        } else if (j < 864) {
            int id = j - 848;
            transpose_tile2((float*)SMEM, Wq, 128, Wcat, 768, (id & 3) * 32, (id >> 2) * 32, 0.25f);
        } else if (j < 904) {
            // Wcat[:,128:768] = (W2 @ Wq[128:,:])^T * 0.25 ; k-outer, LDS W2
            float* w2s = (float*)SMEM;   // 16*128 f32 = 8 KB
            int j0 = (j - 864) * 16;
            for (int idx = t; idx < 16 * 128; idx += 256)
                w2s[idx] = W2[(size_t)j0 * 128 + idx];
            __syncthreads();
            int n = t & 127, half = t >> 7;
            float acc[8];
            #pragma unroll
            for (int jj = 0; jj < 8; ++jj) acc[jj] = 0.f;
            const float* wqp = Wq + (size_t)128 * 128 + n;
            #pragma unroll 8
            for (int k = 0; k < 128; ++k) {
                float wq = wqp[(size_t)k * 128];
                #pragma unroll
                for (int jj = 0; jj < 8; ++jj)
                    acc[jj] = fmaf(w2s[(half * 8 + jj) * 128 + k], wq, acc[jj]);
            }
            #pragma unroll
            for (int jj = 0; jj < 8; ++jj)
                Wcat[(size_t)n * 768 + 128 + j0 + half * 8 + jj] =
                    __float2bfloat16(acc[jj] * 0.25f);
        } else if (j < 929) {
            size_t base = (size_t)(j - 904) * 32768 + (size_t)t * 4;
            #pragma unroll 4
            for (int it = 0; it < 32; ++it) {
                size_t i = base + (size_t)it * 1024;
                float4 v = *(const float4*)(enc + i);
                encb[i + 0] = __float2bfloat16(v.x);
                encb[i + 1] = __float2bfloat16(v.y);
                encb[i + 2] = __float2bfloat16(v.z);
                encb[i + 3] = __float2bfloat16(v.w);
            }
        } else if (j == 929) {
            // bq = (b2 @ Wq[128:,:]) * 0.25 ; k split across两 halves via LDS
            float* red = (float*)SMEM;
            int n = t & 127, half = t >> 7;
            float a0 = 0.f, a1 = 0.f;
            int kb = half * 64;
            #pragma unroll 8
            for (int k = 0; k < 64; k += 2) {
                a0 = fmaf(b2[kb + k],     Wq[(size_t)(128 + kb + k) * 128 + n], a0);
                a1 = fmaf(b2[kb + k + 1], Wq[(size_t)(128 + kb + k + 1) * 128 + n], a1);
            }
            if (half) red[n] = a0 + a1;
            __syncthreads();
            if (!half) bq[n] = (a0 + a1 + red[n]) * 0.25f;
        } else {
            // kNN role: wave-per-row, register-only
            int br = (j - 930) * 4 + wave;
            int b = br / Rc;
            int c = cur[br];
            const float* drow = dist + ((size_t)b * Nc + c) * Nc;
            const float* mrow = maskp + (size_t)br * Nc;

            float v[4];
            #pragma unroll
            for (int jj = 0; jj < 4; ++jj) {
                int n = lane + 64 * jj;
                bool allowed = false;
                float val = INFINITY;
                if (n < Nc) {
                    float mv = mrow[n];
                    if (!isinf(mv)) { val = drow[n]; allowed = true; }
                }
                v[jj] = val;
                u64 wb = __ballot(allowed);
                if (lane == 0) maskbits[(size_t)br * 4 + jj] = wb;
            }
            int idxs[Kc];
            unsigned myrow = 0;
            #pragma unroll
            for (int k = 0; k < Kc; ++k) {
                float bv = v[0]; int bn = lane;
                #pragma unroll
                for (int jj = 1; jj < 4; ++jj) {
                    if (v[jj] < bv) { bv = v[jj]; bn = lane + 64 * jj; }
                }
                #pragma unroll
                for (int off = 32; off > 0; off >>= 1) {
                    float ov = __shfl_xor(bv, off);
                    int   on = __shfl_xor(bn, off);
                    if (ov < bv || (ov == bv && on < bn)) { bv = ov; bn = on; }
                }
                bool pad = isinf(bv);
                idxs[k] = pad ? Nc : bn;
                if (lane == k) myrow = pad ? (unsigned)(Bc * Nc + br) : (unsigned)(b * Nc + bn);
                int oj = bn >> 6, ol = bn & 63;
                if (!pad && lane == ol) v[oj] = INFINITY;
            }
            if (lane < Kc) aoff[(size_t)br * 16 + lane] = myrow << 7;

            const float* erow = enc + ((size_t)b * Nc + c) * Dc;
            __hip_bfloat16* hrow = hq + (size_t)br * 768;
            hrow[lane]      = __float2bfloat16(erow[lane]);
            hrow[lane + 64] = __float2bfloat16(erow[lane + 64]);

            if (idxs[Kc - 1] == Nc) {
                float cnt = 0.f;
                #pragma unroll
                for (int k = 0; k < Kc; ++k) cnt += (idxs[k] < Nc) ? 1.f : 0.f;
                float icnt = 1.f / fmaxf(cnt, 1e-9f);
                #pragma unroll
                for (int half = 0; half < 2; ++half) {
                    int d = lane + 64 * half;
                    float sum = 0.f;
                    #pragma unroll
                    for (int k = 0; k < Kc; ++k) {
                        if (idxs[k] < Nc)
                            sum += enc[((size_t)b * Nc + idxs[k]) * Dc + d];
                    }
                    encb[((size_t)(Bc * Nc) + br) * Dc + d] = __float2bfloat16(sum * icnt);
                }
            }
        }
        __syncthreads();   // LDS reuse guard between job iterations
    }
    grid_sync(bar, GRID);

    // ======================= P1: gemm1 + kvf + em + be ===================
    {
        short* Asl = (short*)SMEM;              // [4][64*32]
        short* Bsl = (short*)(SMEM + 16384);    // [4][64*32]
        for (int j = blockIdx.x; j < 1625; j += GRID) {
            if (j < 1000) {
                int m0 = (j / 10) * 64, n0 = (j % 10) * 64;
                unsigned o0[Kc], o1[Kc];
                if (wave < 2) {
                    const unsigned* ap0 = aoff + (size_t)(m0 + strip + lrow) * 16;
                    const unsigned* ap1 = ap0 + 16 * 16;
                    #pragma unroll
                    for (int jj = 0; jj < Kc; ++jj) { o0[jj] = ap0[jj]; o1[jj] = ap1[jj]; }
                }
                const short* Eb = (const short*)encb;
                const short* gB0 = (const short*)W1t + (size_t)(n0 + strip + lrow) * 1280 + gq * 8;
                const short* gB1 = gB0 + (size_t)16 * 1280;

                f32x4 acc[2][2];
                #pragma unroll
                for (int i = 0; i < 2; ++i)
                    #pragma unroll
                    for (int jj = 0; jj < 2; ++jj)
                        acc[i][jj] = (f32x4){0.f, 0.f, 0.f, 0.f};

                #pragma unroll
                for (int kt = 0; kt < 10; ++kt) {
                    __syncthreads();
                    #pragma unroll
                    for (int s = 0; s < 4; ++s) {
                        if (wave < 2) {
                            GLOAD_LDS16(Eb + o0[kt] + s * 32 + gq * 8, Asl + s * 2048 + strip * 32);
                            GLOAD_LDS16(Eb + o1[kt] + s * 32 + gq * 8, Asl + s * 2048 + (strip + 16) * 32);
                        } else {
                            GLOAD_LDS16(gB0 + kt * 128 + s * 32, Bsl + s * 2048 + strip * 32);
                            GLOAD_LDS16(gB1 + kt * 128 + s * 32, Bsl + s * 2048 + (strip + 16) * 32);
                        }
                    }
                    __syncthreads();
                    #pragma unroll
                    for (int s = 0; s < 4; ++s) {
                        short8 afr[2], bfr[2];
                        #pragma unroll
                        for (int mt = 0; mt < 2; ++mt)
                            afr[mt] = *(const short8*)(Asl + s * 2048 + (wm * 32 + mt * 16 + rrow) * 32 + ((quad + srd) & 3) * 8);
                        #pragma unroll
                        for (int nt = 0; nt < 2; ++nt)
                            bfr[nt] = *(const short8*)(Bsl + s * 2048 + (wn * 32 + nt * 16 + rrow) * 32 + ((quad + srd) & 3) * 8);
                        #pragma unroll
                        for (int mt = 0; mt < 2; ++mt)
                            #pragma unroll
                            for (int nt = 0; nt < 2; ++nt)
                                acc[mt][nt] = __builtin_amdgcn_mfma_f32_16x16x32_bf16(
                                    afr[mt], bfr[nt], acc[mt][nt], 0, 0, 0);
                    }
                }
                #pragma unroll
                for (int mt = 0; mt < 2; ++mt)
                    #pragma unroll
                    for (int nt = 0; nt < 2; ++nt) {
                        int n = wn * 32 + nt * 16 + rrow;
                        float bv = b1[n0 + n];
                        #pragma unroll
                        for (int i = 0; i < 4; ++i) {
                            int m = m0 + wm * 32 + mt * 16 + quad * 4 + i;
                            float vv = fmaxf(acc[mt][nt][i] + bv, 0.f);
                            hq[(size_t)m * 768 + 128 + n0 + n] = __float2bfloat16(vv);
                        }
                    }
            } else if (j < 1600) {
                const short* Bbase; __hip_bfloat16* Cout; int ldc, m0, n0;
                if (j < 1400) {
                    int id = j - 1000;
                    Bbase = (const short*)Wkvt; Cout = kvf; ldc = 256;
                    m0 = (id >> 2) * 64; n0 = (id & 3) * 64;
                } else {
                    int id = j - 1400;
                    Bbase = (const short*)Wmb; Cout = em; ldc = 128;
                    m0 = (id >> 1) * 64; n0 = (id & 1) * 64;
                }
                const short* g0 = (wave < 2)
                    ? (const short*)encb + (size_t)(m0 + strip + lrow) * 128 + gq * 8
                    : Bbase + (size_t)(n0 + strip + lrow) * 128 + gq * 8;
                const short* g1 = g0 + (size_t)16 * 128;

                f32x4 acc[2][2];
                #pragma unroll
                for (int i = 0; i < 2; ++i)
                    #pragma unroll
                    for (int jj = 0; jj < 2; ++jj)
                        acc[i][jj] = (f32x4){0.f, 0.f, 0.f, 0.f};

                __syncthreads();   // guard LDS reuse across job iterations
                #pragma unroll
                for (int s = 0; s < 4; ++s) {
                    short* l0 = (wave < 2) ? (Asl + s * 2048 + strip * 32) : (Bsl + s * 2048 + strip * 32);
                    short* l1 = (wave < 2) ? (Asl + s * 2048 + (strip + 16) * 32) : (Bsl + s * 2048 + (strip + 16) * 32);
                    GLOAD_LDS16(g0 + s * 32, l0);
                    GLOAD_LDS16(g1 + s * 32, l1);
                }
                __syncthreads();
                #pragma unroll
                for (int s = 0; s < 4; ++s) {
                    short8 afr[2], bfr[2];
                    #pragma unroll
                    for (int mt = 0; mt < 2; ++mt)
                        afr[mt] = *(const short8*)(Asl + s * 2048 + (wm * 32 + mt * 16 + rrow) * 32 + ((quad + srd) & 3) * 8);
                    #pragma unroll
                    for (int nt = 0; nt < 2; ++nt)
                        bfr[nt] = *(const short8*)(Bsl + s * 2048 + (wn * 32 + nt * 16 + rrow) * 32 + ((quad + srd) & 3) * 8);
                    #pragma unroll
                    for (int mt = 0; mt < 2; ++mt)
                        #pragma unroll
                        for (int nt = 0; nt < 2; ++nt)
                            acc[mt][nt] = __builtin_amdgcn_mfma_f32_16x16x32_bf16(
                                afr[mt], bfr[nt], acc[mt][nt], 0, 0, 0);
                }
                #pragma unroll
                for (int mt = 0; mt < 2; ++mt)
                    #pragma unroll
                    for (int nt = 0; nt < 2; ++nt) {
                        int n = wn * 32 + nt * 16 + rrow;
                        #pragma unroll
                        for (int i = 0; i < 4; ++i) {
                            int m = m0 + wm * 32 + mt * 16 + quad * 4 + i;
                            Cout[(size_t)m * ldc + n0 + n] = __float2bfloat16(acc[mt][nt][i]);
                        }
                    }
            } else {
                int i = (j - 1600) * 256 + t;
                if (i < Bc * Nc) {
                    const float* row = enc + (size_t)i * 128;
                    float acc = 0.f;
                    #pragma unroll
                    for (int dq = 0; dq < 32; ++dq) {
                        float4 e4 = *(const float4*)(row + dq * 4);
                        acc = fmaf(bmhc[dq * 4 + 0], e4.x, acc);
                        acc = fmaf(bmhc[dq * 4 + 1], e4.y, acc);
                        acc = fmaf(bmhc[dq * 4 + 2], e4.z, acc);
                        acc = fmaf(bmhc[dq * 4 + 3], e4.w, acc);
                    }
                    be[i] = acc;
                }
            }
        }
    }
    grid_sync(bar, 2 * GRID);

    // ======================= P2: qgemm ===================================
    if (blockIdx.x < 200) {
        short* Asl = (short*)SMEM;
        short* Bsl = (short*)(SMEM + 16384);
        int m0 = (blockIdx.x >> 1) * 64, n0 = (blockIdx.x & 1) * 64;

        const short* g0 = (wave < 2)
            ? (const short*)hq + (size_t)(m0 + strip + lrow) * 768 + gq * 8
            : (const short*)Wcat + (size_t)(n0 + strip + lrow) * 768 + gq * 8;
        const short* g1 = g0 + (size_t)16 * 768;

        f32x4 acc[2][2];
        #pragma unroll
        for (int i = 0; i < 2; ++i)
            #pragma unroll
            for (int jj = 0; jj < 2; ++jj)
                acc[i][jj] = (f32x4){0.f, 0.f, 0.f, 0.f};

        for (int k0 = 0; k0 < 768; k0 += 128) {
            __syncthreads();
            #pragma unroll
            for (int s = 0; s < 4; ++s) {
                short* l0 = (wave < 2) ? (Asl + s * 2048 + strip * 32) : (Bsl + s * 2048 + strip * 32);
                short* l1 = (wave < 2) ? (Asl + s * 2048 + (strip + 16) * 32) : (Bsl + s * 2048 + (strip + 16) * 32);
                GLOAD_LDS16(g0 + k0 + s * 32, l0);
                GLOAD_LDS16(g1 + k0 + s * 32, l1);
            }
            __syncthreads();
            #pragma unroll
            for (int s = 0; s < 4; ++s) {
                short8 afr[2], bfr[2];
                #pragma unroll
                for (int mt = 0; mt < 2; ++mt)
                    afr[mt] = *(const short8*)(Asl + s * 2048 + (wm * 32 + mt * 16 + rrow) * 32 + ((quad + srd) & 3) * 8);
                #pragma unroll
                for (int nt = 0; nt < 2; ++nt)
                    bfr[nt] = *(const short8*)(Bsl + s * 2048 + (wn * 32 + nt * 16 + rrow) * 32 + ((quad + srd) & 3) * 8);
                #pragma unroll
                for (int mt = 0; mt < 2; ++mt)
                    #pragma unroll
                    for (int nt = 0; nt < 2; ++nt)
                        acc[mt][nt] = __builtin_amdgcn_mfma_f32_16x16x32_bf16(
                            afr[mt], bfr[nt], acc[mt][nt], 0, 0, 0);
            }
        }
        #pragma unroll
        for (int mt = 0; mt < 2; ++mt)
            #pragma unroll
            for (int nt = 0; nt < 2; ++nt) {
                int n = wn * 32 + nt * 16 + rrow;
                float bv = bq[n0 + n];
                #pragma unroll
                for (int i = 0; i < 4; ++i) {
                    int m = m0 + wm * 32 + mt * 16 + quad * 4 + i;
                    q[(size_t)m * 128 + n0 + n] = __float2bfloat16(acc[mt][nt][i] + bv);
                }
            }
    }
    grid_sync(bar, 3 * GRID);

    // ======================= P3: flash attention =========================
    {
        constexpr int RP = 208;
        constexpr int QS = 40;
        constexpr int VS = 232;
        short* Qs = (short*)SMEM;                 // RP*QS
        short* Ks = (short*)(SMEM + 16640);       // RP*QS
        short* Vt = (short*)(SMEM + 33280);       // 16*VS
        short* Ps = (short*)(SMEM + 40704);       // 4 x 16*VS
        u64*  smask = (u64*)(SMEM + 70400);       // RP*4

        int jb = blockIdx.x;
        int half = jb & 1, h = (jb >> 1) & 7, b = jb >> 4;
        short* PsW = Ps + wave * (16 * VS);

        const short8 z8 = {0, 0, 0, 0, 0, 0, 0, 0};
        for (int idx = t; idx < RP * 2; idx += 256) {
            int r = idx >> 1, g = idx & 1;
            short8 qa = z8, ka = z8;
            if (r < Rc) {
                qa = *(const short8*)((const short*)q + ((size_t)(b * Rc + r)) * 128 + h * 16 + g * 8);
                ka = *(const short8*)((const short*)kvf + ((size_t)(b * Nc + r)) * 256 + h * 16 + g * 8);
            }
            *(short8*)&Qs[r * QS + g * 8] = qa;
            *(short8*)&Ks[r * QS + g * 8] = ka;
            *(short8*)&Qs[r * QS + 16 + g * 8] = z8;
            *(short8*)&Ks[r * QS + 16 + g * 8] = z8;
        }
        if (t < Rc) {
            const short* vp = (const short*)kvf + ((size_t)(b * Nc + t)) * 256 + 128 + h * 16;
            short8 v0 = *(const short8*)vp;
            short8 v1 = *(const short8*)(vp + 8);
            #pragma unroll
            for (int d = 0; d < 8; ++d) Vt[d * VS + t] = v0[d];
            #pragma unroll
            for (int d = 0; d < 8; ++d) Vt[(d + 8) * VS + t] = v1[d];
        }
        for (int idx = t; idx < 16 * 32; idx += 256) {
            int d = idx >> 5, cN = 200 + (idx & 31);
            if (cN < VS) Vt[d * VS + cN] = 0;
        }
        for (int idx = lane; idx < 16 * 16; idx += 64) {
            int rr = idx >> 4, cc = 208 + (idx & 15);
            PsW[rr * VS + cc] = 0;
        }
        for (int idx = t; idx < RP * 4; idx += 256) {
            int r = idx >> 2, w = idx & 3;
            smask[r * 4 + w] = (r < Rc) ? maskbits[((size_t)b * Rc + r) * 4 + w] : ~0ull;
        }
        __syncthreads();

        int rt0 = half * 7, rt1 = half ? 13 : 7;
        for (int rt = rt0 + wave; rt < rt1; rt += 4) {
            short8 qf = *(const short8*)&Qs[(rt * 16 + rrow) * QS + quad * 8];
            f32x4 sacc[13];
            #pragma unroll
            for (int nt = 0; nt < 13; ++nt) {
                short8 kf = *(const short8*)&Ks[(nt * 16 + rrow) * QS + quad * 8];
                sacc[nt] = __builtin_amdgcn_mfma_f32_16x16x32_bf16(
                    qf, kf, (f32x4){0.f, 0.f, 0.f, 0.f}, 0, 0, 0);
            }
            float inv[4];
            #pragma unroll
            for (int i = 0; i < 4; ++i) {
                int r = rt * 16 + quad * 4 + i;
                u64 wv0 = smask[r * 4 + 0], wv1 = smask[r * 4 + 1];
                u64 wv2 = smask[r * 4 + 2], wv3 = smask[r * 4 + 3];
                float mx = -INFINITY;
                #pragma unroll
                for (int nt = 0; nt < 13; ++nt) {
                    u64 w = (nt < 4) ? wv0 : (nt < 8) ? wv1 : (nt < 12) ? wv2 : wv3;
                    int sh = ((nt & 3) << 4) + rrow;
                    float s = ((w >> sh) & 1ull) ? sacc[nt][i] : -INFINITY;
                    sacc[nt][i] = s;
                    mx = fmaxf(mx, s);
                }
                mx = fmaxf(mx, __shfl_xor(mx, 1));
                mx = fmaxf(mx, __shfl_xor(mx, 2));
                mx = fmaxf(mx, __shfl_xor(mx, 4));
                mx = fmaxf(mx, __shfl_xor(mx, 8));
                float l = 0.f;
                #pragma unroll
                for (int nt = 0; nt < 13; ++nt) {
                    float p = __expf(sacc[nt][i] - mx);
                    sacc[nt][i] = p;
                    l += p;
                }
                l += __shfl_xor(l, 1);
                l += __shfl_xor(l, 2);
                l += __shfl_xor(l, 4);
                l += __shfl_xor(l, 8);
                inv[i] = (l > 0.f) ? 1.f / l : 0.f;
            }
            #pragma unroll
            for (int nt = 0; nt < 13; ++nt)
                #pragma unroll
                for (int i = 0; i < 4; ++i)
                    *(__hip_bfloat16*)&PsW[(quad * 4 + i) * VS + nt * 16 + rrow] =
                        __float2bfloat16(sacc[nt][i]);
            f32x4 oacc = (f32x4){0.f, 0.f, 0.f, 0.f};
            #pragma unroll
            for (int kt = 0; kt < 7; ++kt) {
                short8 pf = *(const short8*)&PsW[rrow * VS + kt * 32 + quad * 8];
                short8 vf = *(const short8*)&Vt[rrow * VS + kt * 32 + quad * 8];
                oacc = __builtin_amdgcn_mfma_f32_16x16x32_bf16(pf, vf, oacc, 0, 0, 0);
            }
            #pragma unroll
            for (int i = 0; i < 4; ++i) {
                int r = rt * 16 + quad * 4 + i;
                if (r < Rc)
                    att[((size_t)(b * Rc + r)) * 128 + h * 16 + rrow] =
                        __float2bfloat16(oacc[i] * inv[i]);
            }
        }
    }
    grid_sync(bar, 4 * GRID);

    // ======================= P4: logits + softmax ========================
    if (blockIdx.x < 128) {
        short* Asl = (short*)SMEM;              // [4][64*32]
        short* Bsl = (short*)(SMEM + 16384);    // [4][208*32]
        u64*  sm  = (u64*)(SMEM + 69632);       // [64][4]
        float* sbe = (float*)(SMEM + 71680);    // [208]

        int b = blockIdx.x >> 2, m0 = (blockIdx.x & 3) * 64;

        const short* Aa = (const short*)att + ((size_t)b * Rc + m0) * 128;
        const short* Ben = (const short*)em + (size_t)b * Nc * 128;

        #pragma unroll
        for (int kc = 0; kc < 4; ++kc)
            GLOAD_LDS16(Aa + (size_t)(wave * 16 + lrow) * 128 + kc * 32 + gq * 8,
                        Asl + kc * 2048 + (wave * 16) * 32);
        for (int cch = wave; cch < 13; cch += 4)
            #pragma unroll
            for (int kc = 0; kc < 4; ++kc)
                GLOAD_LDS16(Ben + (size_t)(cch * 16 + lrow) * 128 + kc * 32 + gq * 8,
                            Bsl + kc * 208 * 32 + (cch * 16) * 32);
        {
            int r = t >> 2, w = t & 3;   // 256 threads = 64 rows x 4 words
            sm[r * 4 + w] = (m0 + r < Rc) ? maskbits[((size_t)b * Rc + m0 + r) * 4 + w] : 0ull;
        }
        if (t < 208) sbe[t] = (t < Nc) ? be[(size_t)b * Nc + t] : 0.f;
        __syncthreads();

        short8 afr[4];
        #pragma unroll
        for (int kc = 0; kc < 4; ++kc)
            afr[kc] = *(const short8*)(Asl + kc * 2048 + (wave * 16 + rrow) * 32 + ((quad + srd) & 3) * 8);

        f32x4 acc[13];
        #pragma unroll
        for (int nt = 0; nt < 13; ++nt)
            acc[nt] = (f32x4){0.f, 0.f, 0.f, 0.f};
        #pragma unroll
        for (int nt = 0; nt < 13; ++nt)
            #pragma unroll
            for (int kc = 0; kc < 4; ++kc) {
                short8 bfr = *(const short8*)
                    (Bsl + kc * 208 * 32 + (nt * 16 + rrow) * 32 + ((quad + srd) & 3) * 8);
                acc[nt] = __builtin_amdgcn_mfma_f32_16x16x32_bf16(afr[kc], bfr, acc[nt], 0, 0, 0);
            }

        const float scale = 0.08838834764831843f;  // 1/sqrt(128)
        #pragma unroll
        for (int i = 0; i < 4; ++i) {
            int rloc = wave * 16 + quad * 4 + i;
            int r = m0 + rloc;
            u64 w0 = sm[rloc * 4 + 0], w1 = sm[rloc * 4 + 1];
            u64 w2 = sm[rloc * 4 + 2], w3 = sm[rloc * 4 + 3];
            float vals[13];
            float mx = -INFINITY;
            #pragma unroll
            for (int nt = 0; nt < 13; ++nt) {
                u64 w = (nt < 4) ? w0 : (nt < 8) ? w1 : (nt < 12) ? w2 : w3;
                int sh = ((nt & 3) << 4) + rrow;
                float lg = ((w >> sh) & 1ull)
                         ? 10.f * tanhf((acc[nt][i] + sbe[nt * 16 + rrow]) * scale)
                         : -INFINITY;
                vals[nt] = lg;
                mx = fmaxf(mx, lg);
            }
            mx = fmaxf(mx, __shfl_xor(mx, 1));
            mx = fmaxf(mx, __shfl_xor(mx, 2));
            mx = fmaxf(mx, __shfl_xor(mx, 4));
            mx = fmaxf(mx, __shfl_xor(mx, 8));
            float l = 0.f;
            #pragma unroll
            for (int nt = 0; nt < 13; ++nt) {
                float p = (vals[nt] == -INFINITY) ? 0.f : __expf(vals[nt] - mx);
                vals[nt] = p;
                l += p;
            }
            l += __shfl_xor(l, 1);
            l += __shfl_xor(l, 2);
            l += __shfl_xor(l, 4);
            l += __shfl_xor(l, 8);
            float inv = (l > 0.f) ? 1.f / l : 0.f;
            if (r < Rc) {
                #pragma unroll
                for (int nt = 0; nt < 13; ++nt) {
                    int n = nt * 16 + rrow;
                    if (n < Nc)
                        out[((size_t)b * Rc + r) * Nc + n] = vals[nt] * inv;
                }
            }
        }
    }
}

// ---------------------------------------------------------------------------
extern "C" void kernel_launch(void* const* d_in, const int* in_sizes, int n_in,
                              void* d_out, int out_size, void* d_ws, size_t ws_size,
                              hipStream_t stream)
{
    const float* enc  = (const float*)d_in[0];
    const float* dist = (const float*)d_in[1];
    const float* mask = (const float*)d_in[2];
    const int*   cur  = (const int*)d_in[3];
    const float* Wq   = (const float*)d_in[4];
    const float* Wk   = (const float*)d_in[5];
    const float* Wv   = (const float*)d_in[6];
    const float* Wmhc = (const float*)d_in[7];
    const float* bmhc = (const float*)d_in[8];
    const float* W1   = (const float*)d_in[9];
    const float* b1   = (const float*)d_in[10];
    const float* W2   = (const float*)d_in[11];
    const float* b2   = (const float*)d_in[12];
    float* out = (float*)d_out;

    char* ws = (char*)d_ws;
    size_t off = 0;
    auto alloc = [&](size_t bytes) { char* p = ws + off; off += (bytes + 255) & ~(size_t)255; return p; };
    unsigned* bar = (unsigned*)alloc(256);
    __hip_bfloat16* W1t  = (__hip_bfloat16*)alloc((size_t)640 * 1280 * 2);
    __hip_bfloat16* Wkvt = (__hip_bfloat16*)alloc((size_t)256 * 128 * 2);
    __hip_bfloat16* Wmb  = (__hip_bfloat16*)alloc((size_t)128 * 128 * 2);
    __hip_bfloat16* Wcat = (__hip_bfloat16*)alloc((size_t)128 * 768 * 2);
    float* bq = (float*)alloc((size_t)128 * 4);
    __hip_bfloat16* encb = (__hip_bfloat16*)alloc((size_t)(Bc * Nc + BRc + 64) * Dc * 2);
    unsigned* aoff = (unsigned*)alloc((size_t)BRc * 16 * 4);
    __hip_bfloat16* hq   = (__hip_bfloat16*)alloc((size_t)BRc * 768 * 2);
    __hip_bfloat16* q    = (__hip_bfloat16*)alloc((size_t)BRc * 128 * 2);
    __hip_bfloat16* kvf  = (__hip_bfloat16*)alloc((size_t)Bc * Nc * 256 * 2);
    __hip_bfloat16* att  = (__hip_bfloat16*)alloc((size_t)(BRc + 64) * 128 * 2);
    __hip_bfloat16* em   = (__hip_bfloat16*)alloc((size_t)(Bc * Nc + 64) * 128 * 2);
    float* be = (float*)alloc((size_t)Bc * Nc * 4);
    u64* maskbits = (u64*)alloc((size_t)BRc * 4 * 8);

    hipMemsetAsync(bar, 0, 256, stream);
    mega_kernel<<<GRID, 256, 0, stream>>>(
        W1, W2, Wq, Wmhc, Wk, Wv, bmhc, b1, b2, enc, dist, mask, cur,
        W1t, Wkvt, Wmb, Wcat, bq, encb, aoff, hq, q, kvf, att, em, be,
        maskbits, out, bar);
}

// Round 5
// 162.312 us; speedup vs baseline: 2.7175x; 2.7175x over previous
//
#include <hip/hip_runtime.h>
#include <hip/hip_bf16.h>
#include <math.h>

#define Bc 32
#define Rc 200
#define Nc 200
#define Dc 128
#define Hc 8
#define QKc 16
#define Kc 10
#define BRc (Bc*Rc)

typedef __attribute__((ext_vector_type(8))) short short8;
typedef __attribute__((ext_vector_type(4))) float f32x4;
typedef unsigned long long u64;

#define GLOAD_LDS16(g, l) __builtin_amdgcn_global_load_lds( \
    (const __attribute__((address_space(1))) void*)(g), \
    (__attribute__((address_space(3))) void*)(l), 16, 0, 0)

// ---------------------------------------------------------------------------
// 32x32 transpose+convert tile helper (block-uniform call sites only)
// ---------------------------------------------------------------------------
__device__ inline void transpose_tile(const float* __restrict__ src, int lds_,
                                      __hip_bfloat16* __restrict__ dst, int ldd,
                                      int k0, int n0, float scale)
{
    __shared__ float tile[32][33];
    int tx = threadIdx.x & 31, ty = threadIdx.x >> 5;  // 32 x 8
    #pragma unroll
    for (int i = ty; i < 32; i += 8)
        tile[i][tx] = src[(size_t)(k0 + i) * lds_ + n0 + tx];
    __syncthreads();
    #pragma unroll
    for (int i = ty; i < 32; i += 8)
        dst[(size_t)(n0 + i) * ldd + k0 + tx] = __float2bfloat16(tile[tx][i] * scale);
}

// ---------------------------------------------------------------------------
// Kernel 1: prep + kNN fused (independent roles, one launch).
// ---------------------------------------------------------------------------
__global__ __launch_bounds__(256) void prep_knn_kernel(
    const float* __restrict__ W1, const float* __restrict__ W2,
    const float* __restrict__ Wq, const float* __restrict__ Wmhc,
    const float* __restrict__ Wk, const float* __restrict__ Wv,
    const float* __restrict__ b2, const float* __restrict__ enc,
    const float* __restrict__ dist, const float* __restrict__ mask,
    const int* __restrict__ cur,
    __hip_bfloat16* __restrict__ W1t, __hip_bfloat16* __restrict__ Wkvt,
    __hip_bfloat16* __restrict__ Wmb, __hip_bfloat16* __restrict__ Wcat,
    float* __restrict__ bq, __hip_bfloat16* __restrict__ encb,
    unsigned* __restrict__ aoff, __hip_bfloat16* __restrict__ hq,
    u64* __restrict__ maskbits)
{
    int bid = blockIdx.x;
    int t = threadIdx.x;
    if (bid < 800) {
        transpose_tile(W1, 640, W1t, 1280, (bid % 40) * 32, (bid / 40) * 32, 1.f);
    } else if (bid < 816) {
        int id = bid - 800;
        transpose_tile(Wk, 128, Wkvt, 128, (id & 3) * 32, (id >> 2) * 32, 1.f);
    } else if (bid < 832) {
        int id = bid - 816;
        transpose_tile(Wv, 128, Wkvt + 128 * 128, 128, (id & 3) * 32, (id >> 2) * 32, 1.f);
    } else if (bid < 848) {
        int e = (bid - 832) * 1024 + t * 4;
        #pragma unroll
        for (int j = 0; j < 4; ++j) Wmb[e + j] = __float2bfloat16(Wmhc[e + j]);
    } else if (bid < 864) {
        int id = bid - 848;
        transpose_tile(Wq, 128, Wcat, 768, (id & 3) * 32, (id >> 2) * 32, 0.25f);
    } else if (bid < 904) {
        // ---- Wcat[:,128:768] = (W2 @ Wq[128:,:])^T * 0.25
        // k-outer: 1 coalesced Wq load feeds 8 independent accumulators;
        // W2 tile staged in LDS (broadcast reads).
        __shared__ float w2s[16 * 128];
        int j0 = (bid - 864) * 16;
        #pragma unroll
        for (int idx = t; idx < 16 * 128; idx += 256)
            w2s[idx] = W2[(size_t)j0 * 128 + idx];
        __syncthreads();
        int n = t & 127, half = t >> 7;
        float acc[8];
        #pragma unroll
        for (int jj = 0; jj < 8; ++jj) acc[jj] = 0.f;
        const float* wqp = Wq + (size_t)128 * 128 + n;
        #pragma unroll 8
        for (int k = 0; k < 128; ++k) {
            float wq = wqp[(size_t)k * 128];
            #pragma unroll
            for (int jj = 0; jj < 8; ++jj)
                acc[jj] = fmaf(w2s[(half * 8 + jj) * 128 + k], wq, acc[jj]);
        }
        #pragma unroll
        for (int jj = 0; jj < 8; ++jj)
            Wcat[(size_t)n * 768 + 128 + j0 + half * 8 + jj] =
                __float2bfloat16(acc[jj] * 0.25f);
    } else if (bid < 929) {
        size_t base = (size_t)(bid - 904) * 32768 + (size_t)t * 4;
        #pragma unroll 4
        for (int it = 0; it < 32; ++it) {
            size_t i = base + (size_t)it * 1024;
            float4 v = *(const float4*)(enc + i);
            encb[i + 0] = __float2bfloat16(v.x);
            encb[i + 1] = __float2bfloat16(v.y);
            encb[i + 2] = __float2bfloat16(v.z);
            encb[i + 3] = __float2bfloat16(v.w);
        }
    } else if (bid == 929) {
        // ---- bq = (b2 @ Wq[128:,:]) * 0.25 ; split k across two halves.
        __shared__ float red[128];
        int n = t & 127, half = t >> 7;
        float a0 = 0.f, a1 = 0.f;
        int kb = half * 64;
        #pragma unroll 8
        for (int k = 0; k < 64; k += 2) {
            a0 = fmaf(b2[kb + k],     Wq[(size_t)(128 + kb + k) * 128 + n], a0);
            a1 = fmaf(b2[kb + k + 1], Wq[(size_t)(128 + kb + k + 1) * 128 + n], a1);
        }
        if (half) red[n] = a0 + a1;
        __syncthreads();
        if (!half) bq[n] = (a0 + a1 + red[n]) * 0.25f;
    } else {
        // kNN role: wave-per-row, register-only
        int lane = t & 63, w = t >> 6;
        int br = (bid - 930) * 4 + w;
        int b = br / Rc;
        int c = cur[br];
        const float* drow = dist + ((size_t)b * Nc + c) * Nc;
        const float* mrow = mask + (size_t)br * Nc;

        float v[4];
        #pragma unroll
        for (int j = 0; j < 4; ++j) {
            int n = lane + 64 * j;
            bool allowed = false;
            float val = INFINITY;
            if (n < Nc) {
                float mv = mrow[n];
                if (!isinf(mv)) { val = drow[n]; allowed = true; }
            }
            v[j] = val;
            u64 wb = __ballot(allowed);
            if (lane == 0) maskbits[(size_t)br * 4 + j] = wb;
        }
        int idxs[Kc];
        unsigned myrow = 0;
        #pragma unroll
        for (int k = 0; k < Kc; ++k) {
            float bv = v[0]; int bn = lane;
            #pragma unroll
            for (int j = 1; j < 4; ++j) {
                if (v[j] < bv) { bv = v[j]; bn = lane + 64 * j; }
            }
            #pragma unroll
            for (int off = 32; off > 0; off >>= 1) {
                float ov = __shfl_xor(bv, off);
                int   on = __shfl_xor(bn, off);
                if (ov < bv || (ov == bv && on < bn)) { bv = ov; bn = on; }
            }
            bool pad = isinf(bv);
            idxs[k] = pad ? Nc : bn;
            if (lane == k) myrow = pad ? (unsigned)(Bc * Nc + br) : (unsigned)(b * Nc + bn);
            int oj = bn >> 6, ol = bn & 63;
            if (!pad && lane == ol) v[oj] = INFINITY;
        }
        if (lane < Kc) aoff[(size_t)br * 16 + lane] = myrow << 7;

        const float* erow = enc + ((size_t)b * Nc + c) * Dc;
        __hip_bfloat16* hrow = hq + (size_t)br * 768;
        hrow[lane]      = __float2bfloat16(erow[lane]);
        hrow[lane + 64] = __float2bfloat16(erow[lane + 64]);

        if (idxs[Kc - 1] == Nc) {   // wave-uniform cold path: pads exist
            float cnt = 0.f;
            #pragma unroll
            for (int k = 0; k < Kc; ++k) cnt += (idxs[k] < Nc) ? 1.f : 0.f;
            float icnt = 1.f / fmaxf(cnt, 1e-9f);
            #pragma unroll
            for (int half = 0; half < 2; ++half) {
                int d = lane + 64 * half;
                float sum = 0.f;
                #pragma unroll
                for (int k = 0; k < Kc; ++k) {
                    if (idxs[k] < Nc)
                        sum += enc[((size_t)b * Nc + idxs[k]) * Dc + d];
                }
                encb[((size_t)(Bc * Nc) + br) * Dc + d] = __float2bfloat16(sum * icnt);
            }
        }
    }
}

// ---------------------------------------------------------------------------
// Kernel 2: mid-pipeline GEMMs, 64x64 tiles, BK=128:
//  [0,1000)    gemm1: hq[:,128:768] = relu(gather(encb) @ W1t^T + b1), K=1280
//  [1000,1400) kvf = encb @ [Wk|Wv]^T  (K=128)
//  [1400,1600) em  = encb @ Wmb^T      (K=128)
//  [1600,1625) be[i] = bmhc . enc[i]
// ---------------------------------------------------------------------------
__global__ __launch_bounds__(256) void fused_gemms_kernel(
    const __hip_bfloat16* __restrict__ encb, const unsigned* __restrict__ aoff,
    const __hip_bfloat16* __restrict__ W1t, const float* __restrict__ b1,
    const __hip_bfloat16* __restrict__ Wkvt, const __hip_bfloat16* __restrict__ Wmb,
    const float* __restrict__ bmhc, const float* __restrict__ enc,
    __hip_bfloat16* __restrict__ hq, __hip_bfloat16* __restrict__ kvf,
    __hip_bfloat16* __restrict__ em, float* __restrict__ be)
{
    __shared__ short Asl[4][64 * 32];   // 16 KB
    __shared__ short Bsl[4][64 * 32];   // 16 KB
    int bid = blockIdx.x;
    int tid = threadIdx.x;
    int wave = tid >> 6, lane = tid & 63;
    int lrow = lane >> 2;
    int cg   = lane & 3;
    int ss   = (lane >> 3) & 3;
    int gq   = (cg - ss) & 3;
    int wm = wave >> 1, wn = wave & 1;
    int rrow = lane & 15, quad = lane >> 4;
    int srd  = (rrow >> 1) & 3;
    int strip = (wave & 1) * 32;   // staging strip for this wave's operand

    if (bid < 1000) {
        // ---- gemm1 (gather A, K=1280, 10 barrier iters of BK=128)
        int m0 = (bid / 10) * 64, n0 = (bid % 10) * 64;
        unsigned o0[Kc], o1[Kc];
        if (wave < 2) {
            const unsigned* ap0 = aoff + (size_t)(m0 + strip + lrow) * 16;
            const unsigned* ap1 = ap0 + 16 * 16;
            #pragma unroll
            for (int j = 0; j < Kc; ++j) { o0[j] = ap0[j]; o1[j] = ap1[j]; }
        }
        const short* Eb = (const short*)encb;
        const short* gB0 = (const short*)W1t + (size_t)(n0 + strip + lrow) * 1280 + gq * 8;
        const short* gB1 = gB0 + (size_t)16 * 1280;

        f32x4 acc[2][2];
        #pragma unroll
        for (int i = 0; i < 2; ++i)
            #pragma unroll
            for (int j = 0; j < 2; ++j)
                acc[i][j] = (f32x4){0.f, 0.f, 0.f, 0.f};

        #pragma unroll
        for (int kt = 0; kt < 10; ++kt) {
            __syncthreads();
            #pragma unroll
            for (int s = 0; s < 4; ++s) {
                if (wave < 2) {
                    GLOAD_LDS16(Eb + o0[kt] + s * 32 + gq * 8, &Asl[s][strip * 32]);
                    GLOAD_LDS16(Eb + o1[kt] + s * 32 + gq * 8, &Asl[s][(strip + 16) * 32]);
                } else {
                    GLOAD_LDS16(gB0 + kt * 128 + s * 32, &Bsl[s][strip * 32]);
                    GLOAD_LDS16(gB1 + kt * 128 + s * 32, &Bsl[s][(strip + 16) * 32]);
                }
            }
            __syncthreads();
            #pragma unroll
            for (int s = 0; s < 4; ++s) {
                short8 afr[2], bfr[2];
                #pragma unroll
                for (int mt = 0; mt < 2; ++mt)
                    afr[mt] = *(const short8*)&Asl[s][(wm * 32 + mt * 16 + rrow) * 32 + ((quad + srd) & 3) * 8];
                #pragma unroll
                for (int nt = 0; nt < 2; ++nt)
                    bfr[nt] = *(const short8*)&Bsl[s][(wn * 32 + nt * 16 + rrow) * 32 + ((quad + srd) & 3) * 8];
                #pragma unroll
                for (int mt = 0; mt < 2; ++mt)
                    #pragma unroll
                    for (int nt = 0; nt < 2; ++nt)
                        acc[mt][nt] = __builtin_amdgcn_mfma_f32_16x16x32_bf16(
                            afr[mt], bfr[nt], acc[mt][nt], 0, 0, 0);
            }
        }
        #pragma unroll
        for (int mt = 0; mt < 2; ++mt)
            #pragma unroll
            for (int nt = 0; nt < 2; ++nt) {
                int n = wn * 32 + nt * 16 + rrow;
                float bv = b1[n0 + n];
                #pragma unroll
                for (int i = 0; i < 4; ++i) {
                    int m = m0 + wm * 32 + mt * 16 + quad * 4 + i;
                    float vv = fmaxf(acc[mt][nt][i] + bv, 0.f);
                    hq[(size_t)m * 768 + 128 + n0 + n] = __float2bfloat16(vv);
                }
            }
    } else if (bid < 1600) {
        // ---- kvf or em (K=128, SINGLE barrier)
        const short* Bbase; __hip_bfloat16* Cout; int ldc, m0, n0;
        if (bid < 1400) {
            int id = bid - 1000;
            Bbase = (const short*)Wkvt; Cout = kvf; ldc = 256;
            m0 = (id >> 2) * 64; n0 = (id & 3) * 64;
        } else {
            int id = bid - 1400;
            Bbase = (const short*)Wmb; Cout = em; ldc = 128;
            m0 = (id >> 1) * 64; n0 = (id & 1) * 64;
        }
        const short* g0 = (wave < 2)
            ? (const short*)encb + (size_t)(m0 + strip + lrow) * 128 + gq * 8
            : Bbase + (size_t)(n0 + strip + lrow) * 128 + gq * 8;
        const short* g1 = g0 + (size_t)16 * 128;

        f32x4 acc[2][2];
        #pragma unroll
        for (int i = 0; i < 2; ++i)
            #pragma unroll
            for (int j = 0; j < 2; ++j)
                acc[i][j] = (f32x4){0.f, 0.f, 0.f, 0.f};

        #pragma unroll
        for (int s = 0; s < 4; ++s) {
            short* l0 = (wave < 2) ? &Asl[s][strip * 32] : &Bsl[s][strip * 32];
            short* l1 = (wave < 2) ? &Asl[s][(strip + 16) * 32] : &Bsl[s][(strip + 16) * 32];
            GLOAD_LDS16(g0 + s * 32, l0);
            GLOAD_LDS16(g1 + s * 32, l1);
        }
        __syncthreads();
        #pragma unroll
        for (int s = 0; s < 4; ++s) {
            short8 afr[2], bfr[2];
            #pragma unroll
            for (int mt = 0; mt < 2; ++mt)
                afr[mt] = *(const short8*)&Asl[s][(wm * 32 + mt * 16 + rrow) * 32 + ((quad + srd) & 3) * 8];
            #pragma unroll
            for (int nt = 0; nt < 2; ++nt)
                bfr[nt] = *(const short8*)&Bsl[s][(wn * 32 + nt * 16 + rrow) * 32 + ((quad + srd) & 3) * 8];
            #pragma unroll
            for (int mt = 0; mt < 2; ++mt)
                #pragma unroll
                for (int nt = 0; nt < 2; ++nt)
                    acc[mt][nt] = __builtin_amdgcn_mfma_f32_16x16x32_bf16(
                        afr[mt], bfr[nt], acc[mt][nt], 0, 0, 0);
        }
        #pragma unroll
        for (int mt = 0; mt < 2; ++mt)
            #pragma unroll
            for (int nt = 0; nt < 2; ++nt) {
                int n = wn * 32 + nt * 16 + rrow;
                #pragma unroll
                for (int i = 0; i < 4; ++i) {
                    int m = m0 + wm * 32 + mt * 16 + quad * 4 + i;
                    Cout[(size_t)m * ldc + n0 + n] = __float2bfloat16(acc[mt][nt][i]);
                }
            }
    } else {
        // ---- be[i] = bmhc . enc[i,:]   (i < Bc*Nc = 6400; 25 blocks)
        int i = (bid - 1600) * 256 + tid;
        if (i < Bc * Nc) {
            const float* row = enc + (size_t)i * 128;
            float acc = 0.f;
            #pragma unroll
            for (int dq = 0; dq < 32; ++dq) {
                float4 e4 = *(const float4*)(row + dq * 4);
                acc = fmaf(bmhc[dq * 4 + 0], e4.x, acc);
                acc = fmaf(bmhc[dq * 4 + 1], e4.y, acc);
                acc = fmaf(bmhc[dq * 4 + 2], e4.z, acc);
                acc = fmaf(bmhc[dq * 4 + 3], e4.w, acc);
            }
            be[i] = acc;
        }
    }
}

// ---------------------------------------------------------------------------
// Kernel 3: q = hq @ Wcat^T + bq  (64x64 tiles, BK=128 -> 6 barrier iters)
// ---------------------------------------------------------------------------
__global__ __launch_bounds__(256) void qgemm_kernel(
    const __hip_bfloat16* __restrict__ hq, const __hip_bfloat16* __restrict__ Wcat,
    const float* __restrict__ bq, __hip_bfloat16* __restrict__ q)
{
    __shared__ short Asl[4][64 * 32];
    __shared__ short Bsl[4][64 * 32];
    int tid = threadIdx.x;
    int wave = tid >> 6, lane = tid & 63;
    int m0 = blockIdx.y * 64, n0 = blockIdx.x * 64;
    int lrow = lane >> 2;
    int cg   = lane & 3;
    int ss   = (lane >> 3) & 3;
    int gq   = (cg - ss) & 3;
    int wm = wave >> 1, wn = wave & 1;
    int rrow = lane & 15, quad = lane >> 4;
    int srd  = (rrow >> 1) & 3;
    int strip = (wave & 1) * 32;

    const short* g0 = (wave < 2)
        ? (const short*)hq + (size_t)(m0 + strip + lrow) * 768 + gq * 8
        : (const short*)Wcat + (size_t)(n0 + strip + lrow) * 768 + gq * 8;
    const short* g1 = g0 + (size_t)16 * 768;

    f32x4 acc[2][2];
    #pragma unroll
    for (int i = 0; i < 2; ++i)
        #pragma unroll
        for (int j = 0; j < 2; ++j)
            acc[i][j] = (f32x4){0.f, 0.f, 0.f, 0.f};

    for (int k0 = 0; k0 < 768; k0 += 128) {
        __syncthreads();
        #pragma unroll
        for (int s = 0; s < 4; ++s) {
            short* l0 = (wave < 2) ? &Asl[s][strip * 32] : &Bsl[s][strip * 32];
            short* l1 = (wave < 2) ? &Asl[s][(strip + 16) * 32] : &Bsl[s][(strip + 16) * 32];
            GLOAD_LDS16(g0 + k0 + s * 32, l0);
            GLOAD_LDS16(g1 + k0 + s * 32, l1);
        }
        __syncthreads();
        #pragma unroll
        for (int s = 0; s < 4; ++s) {
            short8 afr[2], bfr[2];
            #pragma unroll
            for (int mt = 0; mt < 2; ++mt)
                afr[mt] = *(const short8*)&Asl[s][(wm * 32 + mt * 16 + rrow) * 32 + ((quad + srd) & 3) * 8];
            #pragma unroll
            for (int nt = 0; nt < 2; ++nt)
                bfr[nt] = *(const short8*)&Bsl[s][(wn * 32 + nt * 16 + rrow) * 32 + ((quad + srd) & 3) * 8];
            #pragma unroll
            for (int mt = 0; mt < 2; ++mt)
                #pragma unroll
                for (int nt = 0; nt < 2; ++nt)
                    acc[mt][nt] = __builtin_amdgcn_mfma_f32_16x16x32_bf16(
                        afr[mt], bfr[nt], acc[mt][nt], 0, 0, 0);
        }
    }

    #pragma unroll
    for (int mt = 0; mt < 2; ++mt) {
        #pragma unroll
        for (int nt = 0; nt < 2; ++nt) {
            int n = wn * 32 + nt * 16 + rrow;
            float bv = bq[n0 + n];
            #pragma unroll
            for (int i = 0; i < 4; ++i) {
                int m = m0 + wm * 32 + mt * 16 + quad * 4 + i;
                q[(size_t)m * 128 + n0 + n] = __float2bfloat16(acc[mt][nt][i] + bv);
            }
        }
    }
}

// ---------------------------------------------------------------------------
// Kernel 4: MFMA flash attention. Grid (Bc*Hc, 2): blockIdx.y selects the
// row-tile half (tiles 0-6 / 7-12) -> 512 blocks = 2 blocks/CU, 8 waves/CU.
// ---------------------------------------------------------------------------
__global__ __launch_bounds__(256) void attn_mfma_kernel(
    const __hip_bfloat16* __restrict__ q, const __hip_bfloat16* __restrict__ kvf,
    const u64* __restrict__ maskbits, __hip_bfloat16* __restrict__ att)
{
    constexpr int RP = 208;
    constexpr int QS = 40;
    constexpr int VS = 232;
    __shared__ short Qs[RP * QS];
    __shared__ short Ks[RP * QS];
    __shared__ short Vt[16 * VS];
    __shared__ short Ps[4][16 * VS];
    __shared__ u64 smask[RP][4];

    int b = blockIdx.x >> 3, h = blockIdx.x & 7;
    int half = blockIdx.y;
    int t = threadIdx.x;
    int wave = t >> 6, lane = t & 63;
    int rrow = lane & 15, quad = lane >> 4;

    const short8 z8 = {0, 0, 0, 0, 0, 0, 0, 0};
    for (int idx = t; idx < RP * 2; idx += 256) {
        int r = idx >> 1, g = idx & 1;
        short8 qa = z8, ka = z8;
        if (r < Rc) {
            qa = *(const short8*)((const short*)q + ((size_t)(b * Rc + r)) * 128 + h * 16 + g * 8);
            ka = *(const short8*)((const short*)kvf + ((size_t)(b * Nc + r)) * 256 + h * 16 + g * 8);
        }
        *(short8*)&Qs[r * QS + g * 8] = qa;
        *(short8*)&Ks[r * QS + g * 8] = ka;
        *(short8*)&Qs[r * QS + 16 + g * 8] = z8;
        *(short8*)&Ks[r * QS + 16 + g * 8] = z8;
    }
    if (t < Rc) {
        const short* vp = (const short*)kvf + ((size_t)(b * Nc + t)) * 256 + 128 + h * 16;
        short8 v0 = *(const short8*)vp;
        short8 v1 = *(const short8*)(vp + 8);
        #pragma unroll
        for (int d = 0; d < 8; ++d) Vt[d * VS + t] = v0[d];
        #pragma unroll
        for (int d = 0; d < 8; ++d) Vt[(d + 8) * VS + t] = v1[d];
    }
    for (int idx = t; idx < 16 * 32; idx += 256) {
        int d = idx >> 5, cN = 200 + (idx & 31);
        if (cN < VS) Vt[d * VS + cN] = 0;
    }
    for (int idx = lane; idx < 16 * 16; idx += 64) {
        int rr = idx >> 4, cc = 208 + (idx & 15);
        Ps[wave][rr * VS + cc] = 0;
    }
    for (int idx = t; idx < RP * 4; idx += 256) {
        int r = idx >> 2, w = idx & 3;
        smask[r][w] = (r < Rc) ? maskbits[((size_t)b * Rc + r) * 4 + w] : ~0ull;
    }
    __syncthreads();

    int rt0 = half * 7, rt1 = half ? 13 : 7;
    for (int rt = rt0 + wave; rt < rt1; rt += 4) {
        short8 qf = *(const short8*)&Qs[(rt * 16 + rrow) * QS + quad * 8];
        f32x4 sacc[13];
        #pragma unroll
        for (int nt = 0; nt < 13; ++nt) {
            short8 kf = *(const short8*)&Ks[(nt * 16 + rrow) * QS + quad * 8];
            sacc[nt] = __builtin_amdgcn_mfma_f32_16x16x32_bf16(
                qf, kf, (f32x4){0.f, 0.f, 0.f, 0.f}, 0, 0, 0);
        }
        float inv[4];
        #pragma unroll
        for (int i = 0; i < 4; ++i) {
            int r = rt * 16 + quad * 4 + i;
            u64 wv0 = smask[r][0], wv1 = smask[r][1], wv2 = smask[r][2], wv3 = smask[r][3];
            float mx = -INFINITY;
            #pragma unroll
            for (int nt = 0; nt < 13; ++nt) {
                u64 w = (nt < 4) ? wv0 : (nt < 8) ? wv1 : (nt < 12) ? wv2 : wv3;
                int sh = ((nt & 3) << 4) + rrow;
                float s = ((w >> sh) & 1ull) ? sacc[nt][i] : -INFINITY;
                sacc[nt][i] = s;
                mx = fmaxf(mx, s);
            }
            mx = fmaxf(mx, __shfl_xor(mx, 1));
            mx = fmaxf(mx, __shfl_xor(mx, 2));
            mx = fmaxf(mx, __shfl_xor(mx, 4));
            mx = fmaxf(mx, __shfl_xor(mx, 8));
            float l = 0.f;
            #pragma unroll
            for (int nt = 0; nt < 13; ++nt) {
                float p = __expf(sacc[nt][i] - mx);
                sacc[nt][i] = p;
                l += p;
            }
            l += __shfl_xor(l, 1);
            l += __shfl_xor(l, 2);
            l += __shfl_xor(l, 4);
            l += __shfl_xor(l, 8);
            inv[i] = (l > 0.f) ? 1.f / l : 0.f;
        }
        #pragma unroll
        for (int nt = 0; nt < 13; ++nt)
            #pragma unroll
            for (int i = 0; i < 4; ++i)
                *(__hip_bfloat16*)&Ps[wave][(quad * 4 + i) * VS + nt * 16 + rrow] =
                    __float2bfloat16(sacc[nt][i]);
        f32x4 oacc = (f32x4){0.f, 0.f, 0.f, 0.f};
        #pragma unroll
        for (int kt = 0; kt < 7; ++kt) {
            short8 pf = *(const short8*)&Ps[wave][rrow * VS + kt * 32 + quad * 8];
            short8 vf = *(const short8*)&Vt[rrow * VS + kt * 32 + quad * 8];
            oacc = __builtin_amdgcn_mfma_f32_16x16x32_bf16(pf, vf, oacc, 0, 0, 0);
        }
        #pragma unroll
        for (int i = 0; i < 4; ++i) {
            int r = rt * 16 + quad * 4 + i;
            if (r < Rc)
                att[((size_t)(b * Rc + r)) * 128 + h * 16 + rrow] =
                    __float2bfloat16(oacc[i] * inv[i]);
        }
    }
}

// ---------------------------------------------------------------------------
// Kernel 5: fused logits + softmax. 64-row blocks x 256 threads (4 waves),
// grid (32,4) = 128 blocks -> 2 blocks/CU = 8 waves/CU (2x the old 128-thr
// version) and em[b] panel staged once per 64 rows instead of per 32.
// Fast tanh via __expf: tanh(y) = 1 - 2/(e^{2y}+1).
// ---------------------------------------------------------------------------
__global__ __launch_bounds__(256) void logits_softmax_kernel(
    const __hip_bfloat16* __restrict__ att, const __hip_bfloat16* __restrict__ em,
    const float* __restrict__ be, const u64* __restrict__ maskbits,
    float* __restrict__ out)
{
    __shared__ short Asl[4][64 * 32];    // 16 KB
    __shared__ short Bsl[4][208 * 32];   // 53 KB
    __shared__ u64 sm[64][4];
    __shared__ float sbe[208];
    int b = blockIdx.x, m0 = blockIdx.y * 64;
    int t = threadIdx.x, wave = t >> 6, lane = t & 63;
    int lrow = lane >> 2, cg = lane & 3, ss = (lane >> 3) & 3, gq = (cg - ss) & 3;
    int rrow = lane & 15, quad = lane >> 4, srd = (rrow >> 1) & 3;

    const short* Aa = (const short*)att + ((size_t)b * Rc + m0) * 128;
    const short* Ben = (const short*)em + (size_t)b * Nc * 128;

    #pragma unroll
    for (int kc = 0; kc < 4; ++kc)
        GLOAD_LDS16(Aa + (size_t)(wave * 16 + lrow) * 128 + kc * 32 + gq * 8,
                    &Asl[kc][(wave * 16) * 32]);
    for (int cch = wave; cch < 13; cch += 4)
        #pragma unroll
        for (int kc = 0; kc < 4; ++kc)
            GLOAD_LDS16(Ben + (size_t)(cch * 16 + lrow) * 128 + kc * 32 + gq * 8,
                        &Bsl[kc][(cch * 16) * 32]);
    {
        int r = t >> 2, w = t & 3;   // 256 threads = 64 rows x 4 words
        sm[r][w] = (m0 + r < Rc) ? maskbits[((size_t)b * Rc + m0 + r) * 4 + w] : 0ull;
    }
    if (t < 208) sbe[t] = (t < Nc) ? be[(size_t)b * Nc + t] : 0.f;
    __syncthreads();

    short8 afr[4];
    #pragma unroll
    for (int kc = 0; kc < 4; ++kc)
        afr[kc] = *(const short8*)&Asl[kc][(wave * 16 + rrow) * 32 + ((quad + srd) & 3) * 8];

    f32x4 acc[13];
    #pragma unroll
    for (int nt = 0; nt < 13; ++nt)
        acc[nt] = (f32x4){0.f, 0.f, 0.f, 0.f};
    #pragma unroll
    for (int nt = 0; nt < 13; ++nt)
        #pragma unroll
        for (int kc = 0; kc < 4; ++kc) {
            short8 bfr = *(const short8*)
                &Bsl[kc][(nt * 16 + rrow) * 32 + ((quad + srd) & 3) * 8];
            acc[nt] = __builtin_amdgcn_mfma_f32_16x16x32_bf16(afr[kc], bfr, acc[nt], 0, 0, 0);
        }

    const float scale = 0.08838834764831843f;  // 1/sqrt(128)
    #pragma unroll
    for (int i = 0; i < 4; ++i) {
        int rloc = wave * 16 + quad * 4 + i;
        int r = m0 + rloc;
        u64 w0 = sm[rloc][0], w1 = sm[rloc][1], w2 = sm[rloc][2], w3 = sm[rloc][3];
        float vals[13];
        float mx = -INFINITY;
        #pragma unroll
        for (int nt = 0; nt < 13; ++nt) {
            u64 w = (nt < 4) ? w0 : (nt < 8) ? w1 : (nt < 12) ? w2 : w3;
            int sh = ((nt & 3) << 4) + rrow;
            float lg = -INFINITY;
            if ((w >> sh) & 1ull) {
                float y = (acc[nt][i] + sbe[nt * 16 + rrow]) * scale;
                // tanh(y) = 1 - 2/(e^{2y}+1); exact limits at +-inf, no NaN.
                float e = __expf(2.f * y);
                lg = 10.f * (1.f - 2.f / (e + 1.f));
            }
            vals[nt] = lg;
            mx = fmaxf(mx, lg);
        }
        mx = fmaxf(mx, __shfl_xor(mx, 1));
        mx = fmaxf(mx, __shfl_xor(mx, 2));
        mx = fmaxf(mx, __shfl_xor(mx, 4));
        mx = fmaxf(mx, __shfl_xor(mx, 8));
        float l = 0.f;
        #pragma unroll
        for (int nt = 0; nt < 13; ++nt) {
            float p = (vals[nt] == -INFINITY) ? 0.f : __expf(vals[nt] - mx);
            vals[nt] = p;
            l += p;
        }
        l += __shfl_xor(l, 1);
        l += __shfl_xor(l, 2);
        l += __shfl_xor(l, 4);
        l += __shfl_xor(l, 8);
        float inv = (l > 0.f) ? 1.f / l : 0.f;
        if (r < Rc) {
            #pragma unroll
            for (int nt = 0; nt < 13; ++nt) {
                int n = nt * 16 + rrow;
                if (n < Nc)
                    out[((size_t)b * Rc + r) * Nc + n] = vals[nt] * inv;
            }
        }
    }
}

// ---------------------------------------------------------------------------
extern "C" void kernel_launch(void* const* d_in, const int* in_sizes, int n_in,
                              void* d_out, int out_size, void* d_ws, size_t ws_size,
                              hipStream_t stream)
{
    const float* enc  = (const float*)d_in[0];
    const float* dist = (const float*)d_in[1];
    const float* mask = (const float*)d_in[2];
    const int*   cur  = (const int*)d_in[3];
    const float* Wq   = (const float*)d_in[4];
    const float* Wk   = (const float*)d_in[5];
    const float* Wv   = (const float*)d_in[6];
    const float* Wmhc = (const float*)d_in[7];
    const float* bmhc = (const float*)d_in[8];
    const float* W1   = (const float*)d_in[9];
    const float* b1   = (const float*)d_in[10];
    const float* W2   = (const float*)d_in[11];
    const float* b2   = (const float*)d_in[12];
    float* out = (float*)d_out;

    char* ws = (char*)d_ws;
    size_t off = 0;
    auto alloc = [&](size_t bytes) { char* p = ws + off; off += (bytes + 255) & ~(size_t)255; return p; };
    __hip_bfloat16* W1t  = (__hip_bfloat16*)alloc((size_t)640 * 1280 * 2);
    __hip_bfloat16* Wkvt = (__hip_bfloat16*)alloc((size_t)256 * 128 * 2);
    __hip_bfloat16* Wmb  = (__hip_bfloat16*)alloc((size_t)128 * 128 * 2);
    __hip_bfloat16* Wcat = (__hip_bfloat16*)alloc((size_t)128 * 768 * 2);
    float* bq = (float*)alloc((size_t)128 * 4);
    // encb: rows [0, Bc*Nc) = enc bf16; rows [Bc*Nc, Bc*Nc+BRc) = mean rows
    __hip_bfloat16* encb = (__hip_bfloat16*)alloc((size_t)(Bc * Nc + BRc + 64) * Dc * 2);
    unsigned* aoff = (unsigned*)alloc((size_t)BRc * 16 * 4);
    __hip_bfloat16* hq   = (__hip_bfloat16*)alloc((size_t)BRc * 768 * 2);
    __hip_bfloat16* q    = (__hip_bfloat16*)alloc((size_t)BRc * 128 * 2);
    __hip_bfloat16* kvf  = (__hip_bfloat16*)alloc((size_t)Bc * Nc * 256 * 2);
    __hip_bfloat16* att  = (__hip_bfloat16*)alloc((size_t)(BRc + 64) * 128 * 2);
    __hip_bfloat16* em   = (__hip_bfloat16*)alloc((size_t)(Bc * Nc + 64) * 128 * 2);
    float* be = (float*)alloc((size_t)Bc * Nc * 4);
    u64* maskbits = (u64*)alloc((size_t)BRc * 4 * 8);

    // 1) prep + kNN (independent roles, one launch, 2530 blocks)
    prep_knn_kernel<<<2530, 256, 0, stream>>>(
        W1, W2, Wq, Wmhc, Wk, Wv, b2, enc, dist, mask, cur,
        W1t, Wkvt, Wmb, Wcat, bq, encb, aoff, hq, maskbits);
    // 2) gemm1 + kvf + em + be (BK=128, one launch, 1625 blocks)
    fused_gemms_kernel<<<1625, 256, 0, stream>>>(
        encb, aoff, W1t, b1, Wkvt, Wmb, bmhc, enc, hq, kvf, em, be);
    // 3) q = hq @ Wcat^T + bq  (BK=128, 200 blocks)
    qgemm_kernel<<<dim3(2, BRc / 64), 256, 0, stream>>>(hq, Wcat, bq, q);
    // 4) MFMA flash attention (split row-tile halves: 512 blocks)
    attn_mfma_kernel<<<dim3(Bc * Hc, 2), 256, 0, stream>>>(q, kvf, maskbits, att);
    // 5) fused logits + softmax (64-row blocks x 4 waves, grid (32,4) = 128 blocks)
    logits_softmax_kernel<<<dim3(Bc, 4), 256, 0, stream>>>(att, em, be, maskbits, out);
}

// Round 6
// 161.239 us; speedup vs baseline: 2.7356x; 1.0067x over previous
//
#include <hip/hip_runtime.h>
#include <hip/hip_bf16.h>
#include <math.h>

#define Bc 32
#define Rc 200
#define Nc 200
#define Dc 128
#define Hc 8
#define QKc 16
#define Kc 10
#define BRc (Bc*Rc)

typedef __attribute__((ext_vector_type(8))) short short8;
typedef __attribute__((ext_vector_type(4))) float f32x4;
typedef unsigned long long u64;

#define GLOAD_LDS16(g, l) __builtin_amdgcn_global_load_lds( \
    (const __attribute__((address_space(1))) void*)(g), \
    (__attribute__((address_space(3))) void*)(l), 16, 0, 0)

// ---------------------------------------------------------------------------
// 32x32 transpose+convert tile helper (block-uniform call sites only)
// ---------------------------------------------------------------------------
__device__ inline void transpose_tile(const float* __restrict__ src, int lds_,
                                      __hip_bfloat16* __restrict__ dst, int ldd,
                                      int k0, int n0, float scale)
{
    __shared__ float tile[32][33];
    int tx = threadIdx.x & 31, ty = threadIdx.x >> 5;  // 32 x 8
    #pragma unroll
    for (int i = ty; i < 32; i += 8)
        tile[i][tx] = src[(size_t)(k0 + i) * lds_ + n0 + tx];
    __syncthreads();
    #pragma unroll
    for (int i = ty; i < 32; i += 8)
        dst[(size_t)(n0 + i) * ldd + k0 + tx] = __float2bfloat16(tile[tx][i] * scale);
}

// ---------------------------------------------------------------------------
// Kernel 1: prep + kNN fused (independent roles, one launch).
// ---------------------------------------------------------------------------
__global__ __launch_bounds__(256) void prep_knn_kernel(
    const float* __restrict__ W1, const float* __restrict__ W2,
    const float* __restrict__ Wq, const float* __restrict__ Wmhc,
    const float* __restrict__ Wk, const float* __restrict__ Wv,
    const float* __restrict__ b2, const float* __restrict__ enc,
    const float* __restrict__ dist, const float* __restrict__ mask,
    const int* __restrict__ cur,
    __hip_bfloat16* __restrict__ W1t, __hip_bfloat16* __restrict__ Wkvt,
    __hip_bfloat16* __restrict__ Wmb, __hip_bfloat16* __restrict__ Wcat,
    float* __restrict__ bq, __hip_bfloat16* __restrict__ encb,
    unsigned* __restrict__ aoff, __hip_bfloat16* __restrict__ hq,
    u64* __restrict__ maskbits)
{
    int bid = blockIdx.x;
    int t = threadIdx.x;
    if (bid < 800) {
        transpose_tile(W1, 640, W1t, 1280, (bid % 40) * 32, (bid / 40) * 32, 1.f);
    } else if (bid < 816) {
        int id = bid - 800;
        transpose_tile(Wk, 128, Wkvt, 128, (id & 3) * 32, (id >> 2) * 32, 1.f);
    } else if (bid < 832) {
        int id = bid - 816;
        transpose_tile(Wv, 128, Wkvt + 128 * 128, 128, (id & 3) * 32, (id >> 2) * 32, 1.f);
    } else if (bid < 848) {
        int e = (bid - 832) * 1024 + t * 4;
        #pragma unroll
        for (int j = 0; j < 4; ++j) Wmb[e + j] = __float2bfloat16(Wmhc[e + j]);
    } else if (bid < 864) {
        int id = bid - 848;
        transpose_tile(Wq, 128, Wcat, 768, (id & 3) * 32, (id >> 2) * 32, 0.25f);
    } else if (bid < 904) {
        // ---- Wcat[:,128:768] = (W2 @ Wq[128:,:])^T * 0.25
        // k-outer: 1 coalesced Wq load feeds 8 independent accumulators;
        // W2 tile staged in LDS (broadcast reads).
        __shared__ float w2s[16 * 128];
        int j0 = (bid - 864) * 16;
        #pragma unroll
        for (int idx = t; idx < 16 * 128; idx += 256)
            w2s[idx] = W2[(size_t)j0 * 128 + idx];
        __syncthreads();
        int n = t & 127, half = t >> 7;
        float acc[8];
        #pragma unroll
        for (int jj = 0; jj < 8; ++jj) acc[jj] = 0.f;
        const float* wqp = Wq + (size_t)128 * 128 + n;
        #pragma unroll 8
        for (int k = 0; k < 128; ++k) {
            float wq = wqp[(size_t)k * 128];
            #pragma unroll
            for (int jj = 0; jj < 8; ++jj)
                acc[jj] = fmaf(w2s[(half * 8 + jj) * 128 + k], wq, acc[jj]);
        }
        #pragma unroll
        for (int jj = 0; jj < 8; ++jj)
            Wcat[(size_t)n * 768 + 128 + j0 + half * 8 + jj] =
                __float2bfloat16(acc[jj] * 0.25f);
    } else if (bid < 929) {
        size_t base = (size_t)(bid - 904) * 32768 + (size_t)t * 4;
        #pragma unroll 4
        for (int it = 0; it < 32; ++it) {
            size_t i = base + (size_t)it * 1024;
            float4 v = *(const float4*)(enc + i);
            encb[i + 0] = __float2bfloat16(v.x);
            encb[i + 1] = __float2bfloat16(v.y);
            encb[i + 2] = __float2bfloat16(v.z);
            encb[i + 3] = __float2bfloat16(v.w);
        }
    } else if (bid == 929) {
        // ---- bq = (b2 @ Wq[128:,:]) * 0.25 ; split k across two halves.
        __shared__ float red[128];
        int n = t & 127, half = t >> 7;
        float a0 = 0.f, a1 = 0.f;
        int kb = half * 64;
        #pragma unroll 8
        for (int k = 0; k < 64; k += 2) {
            a0 = fmaf(b2[kb + k],     Wq[(size_t)(128 + kb + k) * 128 + n], a0);
            a1 = fmaf(b2[kb + k + 1], Wq[(size_t)(128 + kb + k + 1) * 128 + n], a1);
        }
        if (half) red[n] = a0 + a1;
        __syncthreads();
        if (!half) bq[n] = (a0 + a1 + red[n]) * 0.25f;
    } else {
        // kNN role: wave-per-row, register-only
        int lane = t & 63, w = t >> 6;
        int br = (bid - 930) * 4 + w;
        int b = br / Rc;
        int c = cur[br];
        const float* drow = dist + ((size_t)b * Nc + c) * Nc;
        const float* mrow = mask + (size_t)br * Nc;

        float v[4];
        #pragma unroll
        for (int j = 0; j < 4; ++j) {
            int n = lane + 64 * j;
            bool allowed = false;
            float val = INFINITY;
            if (n < Nc) {
                float mv = mrow[n];
                if (!isinf(mv)) { val = drow[n]; allowed = true; }
            }
            v[j] = val;
            u64 wb = __ballot(allowed);
            if (lane == 0) maskbits[(size_t)br * 4 + j] = wb;
        }
        int idxs[Kc];
        unsigned myrow = 0;
        #pragma unroll
        for (int k = 0; k < Kc; ++k) {
            float bv = v[0]; int bn = lane;
            #pragma unroll
            for (int j = 1; j < 4; ++j) {
                if (v[j] < bv) { bv = v[j]; bn = lane + 64 * j; }
            }
            #pragma unroll
            for (int off = 32; off > 0; off >>= 1) {
                float ov = __shfl_xor(bv, off);
                int   on = __shfl_xor(bn, off);
                if (ov < bv || (ov == bv && on < bn)) { bv = ov; bn = on; }
            }
            bool pad = isinf(bv);
            idxs[k] = pad ? Nc : bn;
            if (lane == k) myrow = pad ? (unsigned)(Bc * Nc + br) : (unsigned)(b * Nc + bn);
            int oj = bn >> 6, ol = bn & 63;
            if (!pad && lane == ol) v[oj] = INFINITY;
        }
        if (lane < Kc) aoff[(size_t)br * 16 + lane] = myrow << 7;

        const float* erow = enc + ((size_t)b * Nc + c) * Dc;
        __hip_bfloat16* hrow = hq + (size_t)br * 768;
        hrow[lane]      = __float2bfloat16(erow[lane]);
        hrow[lane + 64] = __float2bfloat16(erow[lane + 64]);

        if (idxs[Kc - 1] == Nc) {   // wave-uniform cold path: pads exist
            float cnt = 0.f;
            #pragma unroll
            for (int k = 0; k < Kc; ++k) cnt += (idxs[k] < Nc) ? 1.f : 0.f;
            float icnt = 1.f / fmaxf(cnt, 1e-9f);
            #pragma unroll
            for (int half = 0; half < 2; ++half) {
                int d = lane + 64 * half;
                float sum = 0.f;
                #pragma unroll
                for (int k = 0; k < Kc; ++k) {
                    if (idxs[k] < Nc)
                        sum += enc[((size_t)b * Nc + idxs[k]) * Dc + d];
                }
                encb[((size_t)(Bc * Nc) + br) * Dc + d] = __float2bfloat16(sum * icnt);
            }
        }
    }
}

// ---------------------------------------------------------------------------
// Kernel 2: mid-pipeline GEMMs, 64x64 tiles.
//  [0,1000)    gemm1: K=1280, NEW 2-phase dbuf BK=64 (20 steps, 1 barrier/step,
//              loads for step k+1 issued before compute of step k; same 32 KB LDS)
//  [1000,1400) kvf = encb @ [Wk|Wv]^T  (K=128, single barrier)
//  [1400,1600) em  = encb @ Wmb^T      (K=128, single barrier)
//  [1600,1625) be[i] = bmhc . enc[i]
// ---------------------------------------------------------------------------
__global__ __launch_bounds__(256) void fused_gemms_kernel(
    const __hip_bfloat16* __restrict__ encb, const unsigned* __restrict__ aoff,
    const __hip_bfloat16* __restrict__ W1t, const float* __restrict__ b1,
    const __hip_bfloat16* __restrict__ Wkvt, const __hip_bfloat16* __restrict__ Wmb,
    const float* __restrict__ bmhc, const float* __restrict__ enc,
    __hip_bfloat16* __restrict__ hq, __hip_bfloat16* __restrict__ kvf,
    __hip_bfloat16* __restrict__ em, float* __restrict__ be)
{
    __shared__ short Asl[4][64 * 32];   // 16 KB  (gemm1: [buf*2+s], s in {0,1})
    __shared__ short Bsl[4][64 * 32];   // 16 KB
    int bid = blockIdx.x;
    int tid = threadIdx.x;
    int wave = tid >> 6, lane = tid & 63;
    int lrow = lane >> 2;
    int cg   = lane & 3;
    int ss   = (lane >> 3) & 3;
    int gq   = (cg - ss) & 3;
    int wm = wave >> 1, wn = wave & 1;
    int rrow = lane & 15, quad = lane >> 4;
    int srd  = (rrow >> 1) & 3;
    int strip = (wave & 1) * 32;   // staging strip for this wave's operand

    if (bid < 1000) {
        // ---- gemm1 (gather A, K=1280, 2-phase dbuf, BK=64 -> 20 steps)
        int m0 = (bid / 10) * 64, n0 = (bid % 10) * 64;
        unsigned o0[Kc], o1[Kc];
        if (wave < 2) {
            const unsigned* ap0 = aoff + (size_t)(m0 + strip + lrow) * 16;
            const unsigned* ap1 = ap0 + 16 * 16;
            #pragma unroll
            for (int j = 0; j < Kc; ++j) { o0[j] = ap0[j]; o1[j] = ap1[j]; }
        }
        const short* Eb = (const short*)encb;
        const short* gB0 = (const short*)W1t + (size_t)(n0 + strip + lrow) * 1280 + gq * 8;
        const short* gB1 = gB0 + (size_t)16 * 1280;

        f32x4 acc[2][2];
        #pragma unroll
        for (int i = 0; i < 2; ++i)
            #pragma unroll
            for (int j = 0; j < 2; ++j)
                acc[i][j] = (f32x4){0.f, 0.f, 0.f, 0.f};

        // STAGE(buf, kt): issue BK=64 tile kt into buffer buf (no waits here).
        // A rows: gathered rows o0/o1 (g = kt>>1), halves hh = (kt&1)*64 shorts.
#define G1_STAGE(bsel, kt) do {                                                   \
            int g_ = (kt) >> 1, hh_ = ((kt) & 1) * 64;                            \
            _Pragma("unroll")                                                     \
            for (int s_ = 0; s_ < 2; ++s_) {                                      \
                if (wave < 2) {                                                   \
                    GLOAD_LDS16(Eb + o0[g_] + hh_ + s_ * 32 + gq * 8,             \
                                &Asl[((bsel) << 1) | s_][strip * 32]);            \
                    GLOAD_LDS16(Eb + o1[g_] + hh_ + s_ * 32 + gq * 8,             \
                                &Asl[((bsel) << 1) | s_][(strip + 16) * 32]);     \
                } else {                                                          \
                    GLOAD_LDS16(gB0 + (kt) * 64 + s_ * 32,                        \
                                &Bsl[((bsel) << 1) | s_][strip * 32]);            \
                    GLOAD_LDS16(gB1 + (kt) * 64 + s_ * 32,                        \
                                &Bsl[((bsel) << 1) | s_][(strip + 16) * 32]);     \
                }                                                                 \
            } } while (0)

#define G1_COMPUTE(bsel) do {                                                     \
            _Pragma("unroll")                                                     \
            for (int s_ = 0; s_ < 2; ++s_) {                                      \
                short8 afr[2], bfr[2];                                            \
                _Pragma("unroll")                                                 \
                for (int mt = 0; mt < 2; ++mt)                                    \
                    afr[mt] = *(const short8*)&Asl[((bsel) << 1) | s_]            \
                        [(wm * 32 + mt * 16 + rrow) * 32 + ((quad + srd) & 3) * 8]; \
                _Pragma("unroll")                                                 \
                for (int nt = 0; nt < 2; ++nt)                                    \
                    bfr[nt] = *(const short8*)&Bsl[((bsel) << 1) | s_]            \
                        [(wn * 32 + nt * 16 + rrow) * 32 + ((quad + srd) & 3) * 8]; \
                _Pragma("unroll")                                                 \
                for (int mt = 0; mt < 2; ++mt)                                    \
                    _Pragma("unroll")                                             \
                    for (int nt = 0; nt < 2; ++nt)                                \
                        acc[mt][nt] = __builtin_amdgcn_mfma_f32_16x16x32_bf16(    \
                            afr[mt], bfr[nt], acc[mt][nt], 0, 0, 0);              \
            } } while (0)

        G1_STAGE(0, 0);
        __syncthreads();                        // drain prologue loads
        #pragma unroll
        for (int kt = 0; kt < 19; ++kt) {
            G1_STAGE((kt & 1) ^ 1, kt + 1);     // issue next tile first...
            G1_COMPUTE(kt & 1);                 // ...then compute current under it
            __syncthreads();                    // one vmcnt-drain + barrier per step
        }
        G1_COMPUTE(1);                          // kt = 19
#undef G1_STAGE
#undef G1_COMPUTE

        #pragma unroll
        for (int mt = 0; mt < 2; ++mt)
            #pragma unroll
            for (int nt = 0; nt < 2; ++nt) {
                int n = wn * 32 + nt * 16 + rrow;
                float bv = b1[n0 + n];
                #pragma unroll
                for (int i = 0; i < 4; ++i) {
                    int m = m0 + wm * 32 + mt * 16 + quad * 4 + i;
                    float vv = fmaxf(acc[mt][nt][i] + bv, 0.f);
                    hq[(size_t)m * 768 + 128 + n0 + n] = __float2bfloat16(vv);
                }
            }
    } else if (bid < 1600) {
        // ---- kvf or em (K=128, SINGLE barrier) — unchanged
        const short* Bbase; __hip_bfloat16* Cout; int ldc, m0, n0;
        if (bid < 1400) {
            int id = bid - 1000;
            Bbase = (const short*)Wkvt; Cout = kvf; ldc = 256;
            m0 = (id >> 2) * 64; n0 = (id & 3) * 64;
        } else {
            int id = bid - 1400;
            Bbase = (const short*)Wmb; Cout = em; ldc = 128;
            m0 = (id >> 1) * 64; n0 = (id & 1) * 64;
        }
        const short* g0 = (wave < 2)
            ? (const short*)encb + (size_t)(m0 + strip + lrow) * 128 + gq * 8
            : Bbase + (size_t)(n0 + strip + lrow) * 128 + gq * 8;
        const short* g1 = g0 + (size_t)16 * 128;

        f32x4 acc[2][2];
        #pragma unroll
        for (int i = 0; i < 2; ++i)
            #pragma unroll
            for (int j = 0; j < 2; ++j)
                acc[i][j] = (f32x4){0.f, 0.f, 0.f, 0.f};

        #pragma unroll
        for (int s = 0; s < 4; ++s) {
            short* l0 = (wave < 2) ? &Asl[s][strip * 32] : &Bsl[s][strip * 32];
            short* l1 = (wave < 2) ? &Asl[s][(strip + 16) * 32] : &Bsl[s][(strip + 16) * 32];
            GLOAD_LDS16(g0 + s * 32, l0);
            GLOAD_LDS16(g1 + s * 32, l1);
        }
        __syncthreads();
        #pragma unroll
        for (int s = 0; s < 4; ++s) {
            short8 afr[2], bfr[2];
            #pragma unroll
            for (int mt = 0; mt < 2; ++mt)
                afr[mt] = *(const short8*)&Asl[s][(wm * 32 + mt * 16 + rrow) * 32 + ((quad + srd) & 3) * 8];
            #pragma unroll
            for (int nt = 0; nt < 2; ++nt)
                bfr[nt] = *(const short8*)&Bsl[s][(wn * 32 + nt * 16 + rrow) * 32 + ((quad + srd) & 3) * 8];
            #pragma unroll
            for (int mt = 0; mt < 2; ++mt)
                #pragma unroll
                for (int nt = 0; nt < 2; ++nt)
                    acc[mt][nt] = __builtin_amdgcn_mfma_f32_16x16x32_bf16(
                        afr[mt], bfr[nt], acc[mt][nt], 0, 0, 0);
        }
        #pragma unroll
        for (int mt = 0; mt < 2; ++mt)
            #pragma unroll
            for (int nt = 0; nt < 2; ++nt) {
                int n = wn * 32 + nt * 16 + rrow;
                #pragma unroll
                for (int i = 0; i < 4; ++i) {
                    int m = m0 + wm * 32 + mt * 16 + quad * 4 + i;
                    Cout[(size_t)m * ldc + n0 + n] = __float2bfloat16(acc[mt][nt][i]);
                }
            }
    } else {
        // ---- be[i] = bmhc . enc[i,:]   (i < Bc*Nc = 6400; 25 blocks)
        int i = (bid - 1600) * 256 + tid;
        if (i < Bc * Nc) {
            const float* row = enc + (size_t)i * 128;
            float acc = 0.f;
            #pragma unroll
            for (int dq = 0; dq < 32; ++dq) {
                float4 e4 = *(const float4*)(row + dq * 4);
                acc = fmaf(bmhc[dq * 4 + 0], e4.x, acc);
                acc = fmaf(bmhc[dq * 4 + 1], e4.y, acc);
                acc = fmaf(bmhc[dq * 4 + 2], e4.z, acc);
                acc = fmaf(bmhc[dq * 4 + 3], e4.w, acc);
            }
            be[i] = acc;
        }
    }
}

// ---------------------------------------------------------------------------
// Kernel 3: q = hq @ Wcat^T + bq  (64x64 tiles, 2-phase dbuf BK=64 -> 12 steps)
// ---------------------------------------------------------------------------
__global__ __launch_bounds__(256) void qgemm_kernel(
    const __hip_bfloat16* __restrict__ hq, const __hip_bfloat16* __restrict__ Wcat,
    const float* __restrict__ bq, __hip_bfloat16* __restrict__ q)
{
    __shared__ short Asl[4][64 * 32];
    __shared__ short Bsl[4][64 * 32];
    int tid = threadIdx.x;
    int wave = tid >> 6, lane = tid & 63;
    int m0 = blockIdx.y * 64, n0 = blockIdx.x * 64;
    int lrow = lane >> 2;
    int cg   = lane & 3;
    int ss   = (lane >> 3) & 3;
    int gq   = (cg - ss) & 3;
    int wm = wave >> 1, wn = wave & 1;
    int rrow = lane & 15, quad = lane >> 4;
    int srd  = (rrow >> 1) & 3;
    int strip = (wave & 1) * 32;

    const short* g0 = (wave < 2)
        ? (const short*)hq + (size_t)(m0 + strip + lrow) * 768 + gq * 8
        : (const short*)Wcat + (size_t)(n0 + strip + lrow) * 768 + gq * 8;
    const short* g1 = g0 + (size_t)16 * 768;

    f32x4 acc[2][2];
    #pragma unroll
    for (int i = 0; i < 2; ++i)
        #pragma unroll
        for (int j = 0; j < 2; ++j)
            acc[i][j] = (f32x4){0.f, 0.f, 0.f, 0.f};

#define Q_STAGE(bsel, kt) do {                                                    \
        _Pragma("unroll")                                                         \
        for (int s_ = 0; s_ < 2; ++s_) {                                          \
            short* l0_ = (wave < 2) ? &Asl[((bsel) << 1) | s_][strip * 32]        \
                                    : &Bsl[((bsel) << 1) | s_][strip * 32];       \
            short* l1_ = (wave < 2) ? &Asl[((bsel) << 1) | s_][(strip + 16) * 32] \
                                    : &Bsl[((bsel) << 1) | s_][(strip + 16) * 32];\
            GLOAD_LDS16(g0 + (kt) * 64 + s_ * 32, l0_);                           \
            GLOAD_LDS16(g1 + (kt) * 64 + s_ * 32, l1_);                           \
        } } while (0)

#define Q_COMPUTE(bsel) do {                                                      \
        _Pragma("unroll")                                                         \
        for (int s_ = 0; s_ < 2; ++s_) {                                          \
            short8 afr[2], bfr[2];                                                \
            _Pragma("unroll")                                                     \
            for (int mt = 0; mt < 2; ++mt)                                        \
                afr[mt] = *(const short8*)&Asl[((bsel) << 1) | s_]                \
                    [(wm * 32 + mt * 16 + rrow) * 32 + ((quad + srd) & 3) * 8];   \
            _Pragma("unroll")                                                     \
            for (int nt = 0; nt < 2; ++nt)                                        \
                bfr[nt] = *(const short8*)&Bsl[((bsel) << 1) | s_]                \
                    [(wn * 32 + nt * 16 + rrow) * 32 + ((quad + srd) & 3) * 8];   \
            _Pragma("unroll")                                                     \
            for (int mt = 0; mt < 2; ++mt)                                        \
                _Pragma("unroll")                                                 \
                for (int nt = 0; nt < 2; ++nt)                                    \
                    acc[mt][nt] = __builtin_amdgcn_mfma_f32_16x16x32_bf16(        \
                        afr[mt], bfr[nt], acc[mt][nt], 0, 0, 0);                  \
        } } while (0)

    Q_STAGE(0, 0);
    __syncthreads();
    #pragma unroll
    for (int kt = 0; kt < 11; ++kt) {
        Q_STAGE((kt & 1) ^ 1, kt + 1);
        Q_COMPUTE(kt & 1);
        __syncthreads();
    }
    Q_COMPUTE(1);   // kt = 11
#undef Q_STAGE
#undef Q_COMPUTE

    #pragma unroll
    for (int mt = 0; mt < 2; ++mt) {
        #pragma unroll
        for (int nt = 0; nt < 2; ++nt) {
            int n = wn * 32 + nt * 16 + rrow;
            float bv = bq[n0 + n];
            #pragma unroll
            for (int i = 0; i < 4; ++i) {
                int m = m0 + wm * 32 + mt * 16 + quad * 4 + i;
                q[(size_t)m * 128 + n0 + n] = __float2bfloat16(acc[mt][nt][i] + bv);
            }
        }
    }
}

// ---------------------------------------------------------------------------
// Kernel 4: MFMA flash attention. Grid (Bc*Hc, 2): blockIdx.y selects the
// row-tile half (tiles 0-6 / 7-12) -> 512 blocks = 2 blocks/CU, 8 waves/CU.
// ---------------------------------------------------------------------------
__global__ __launch_bounds__(256) void attn_mfma_kernel(
    const __hip_bfloat16* __restrict__ q, const __hip_bfloat16* __restrict__ kvf,
    const u64* __restrict__ maskbits, __hip_bfloat16* __restrict__ att)
{
    constexpr int RP = 208;
    constexpr int QS = 40;
    constexpr int VS = 232;
    __shared__ short Qs[RP * QS];
    __shared__ short Ks[RP * QS];
    __shared__ short Vt[16 * VS];
    __shared__ short Ps[4][16 * VS];
    __shared__ u64 smask[RP][4];

    int b = blockIdx.x >> 3, h = blockIdx.x & 7;
    int half = blockIdx.y;
    int t = threadIdx.x;
    int wave = t >> 6, lane = t & 63;
    int rrow = lane & 15, quad = lane >> 4;

    const short8 z8 = {0, 0, 0, 0, 0, 0, 0, 0};
    for (int idx = t; idx < RP * 2; idx += 256) {
        int r = idx >> 1, g = idx & 1;
        short8 qa = z8, ka = z8;
        if (r < Rc) {
            qa = *(const short8*)((const short*)q + ((size_t)(b * Rc + r)) * 128 + h * 16 + g * 8);
            ka = *(const short8*)((const short*)kvf + ((size_t)(b * Nc + r)) * 256 + h * 16 + g * 8);
        }
        *(short8*)&Qs[r * QS + g * 8] = qa;
        *(short8*)&Ks[r * QS + g * 8] = ka;
        *(short8*)&Qs[r * QS + 16 + g * 8] = z8;
        *(short8*)&Ks[r * QS + 16 + g * 8] = z8;
    }
    if (t < Rc) {
        const short* vp = (const short*)kvf + ((size_t)(b * Nc + t)) * 256 + 128 + h * 16;
        short8 v0 = *(const short8*)vp;
        short8 v1 = *(const short8*)(vp + 8);
        #pragma unroll
        for (int d = 0; d < 8; ++d) Vt[d * VS + t] = v0[d];
        #pragma unroll
        for (int d = 0; d < 8; ++d) Vt[(d + 8) * VS + t] = v1[d];
    }
    for (int idx = t; idx < 16 * 32; idx += 256) {
        int d = idx >> 5, cN = 200 + (idx & 31);
        if (cN < VS) Vt[d * VS + cN] = 0;
    }
    for (int idx = lane; idx < 16 * 16; idx += 64) {
        int rr = idx >> 4, cc = 208 + (idx & 15);
        Ps[wave][rr * VS + cc] = 0;
    }
    for (int idx = t; idx < RP * 4; idx += 256) {
        int r = idx >> 2, w = idx & 3;
        smask[r][w] = (r < Rc) ? maskbits[((size_t)b * Rc + r) * 4 + w] : ~0ull;
    }
    __syncthreads();

    int rt0 = half * 7, rt1 = half ? 13 : 7;
    for (int rt = rt0 + wave; rt < rt1; rt += 4) {
        short8 qf = *(const short8*)&Qs[(rt * 16 + rrow) * QS + quad * 8];
        f32x4 sacc[13];
        #pragma unroll
        for (int nt = 0; nt < 13; ++nt) {
            short8 kf = *(const short8*)&Ks[(nt * 16 + rrow) * QS + quad * 8];
            sacc[nt] = __builtin_amdgcn_mfma_f32_16x16x32_bf16(
                qf, kf, (f32x4){0.f, 0.f, 0.f, 0.f}, 0, 0, 0);
        }
        float inv[4];
        #pragma unroll
        for (int i = 0; i < 4; ++i) {
            int r = rt * 16 + quad * 4 + i;
            u64 wv0 = smask[r][0], wv1 = smask[r][1], wv2 = smask[r][2], wv3 = smask[r][3];
            float mx = -INFINITY;
            #pragma unroll
            for (int nt = 0; nt < 13; ++nt) {
                u64 w = (nt < 4) ? wv0 : (nt < 8) ? wv1 : (nt < 12) ? wv2 : wv3;
                int sh = ((nt & 3) << 4) + rrow;
                float s = ((w >> sh) & 1ull) ? sacc[nt][i] : -INFINITY;
                sacc[nt][i] = s;
                mx = fmaxf(mx, s);
            }
            mx = fmaxf(mx, __shfl_xor(mx, 1));
            mx = fmaxf(mx, __shfl_xor(mx, 2));
            mx = fmaxf(mx, __shfl_xor(mx, 4));
            mx = fmaxf(mx, __shfl_xor(mx, 8));
            float l = 0.f;
            #pragma unroll
            for (int nt = 0; nt < 13; ++nt) {
                float p = __expf(sacc[nt][i] - mx);
                sacc[nt][i] = p;
                l += p;
            }
            l += __shfl_xor(l, 1);
            l += __shfl_xor(l, 2);
            l += __shfl_xor(l, 4);
            l += __shfl_xor(l, 8);
            inv[i] = (l > 0.f) ? 1.f / l : 0.f;
        }
        #pragma unroll
        for (int nt = 0; nt < 13; ++nt)
            #pragma unroll
            for (int i = 0; i < 4; ++i)
                *(__hip_bfloat16*)&Ps[wave][(quad * 4 + i) * VS + nt * 16 + rrow] =
                    __float2bfloat16(sacc[nt][i]);
        f32x4 oacc = (f32x4){0.f, 0.f, 0.f, 0.f};
        #pragma unroll
        for (int kt = 0; kt < 7; ++kt) {
            short8 pf = *(const short8*)&Ps[wave][rrow * VS + kt * 32 + quad * 8];
            short8 vf = *(const short8*)&Vt[rrow * VS + kt * 32 + quad * 8];
            oacc = __builtin_amdgcn_mfma_f32_16x16x32_bf16(pf, vf, oacc, 0, 0, 0);
        }
        #pragma unroll
        for (int i = 0; i < 4; ++i) {
            int r = rt * 16 + quad * 4 + i;
            if (r < Rc)
                att[((size_t)(b * Rc + r)) * 128 + h * 16 + rrow] =
                    __float2bfloat16(oacc[i] * inv[i]);
        }
    }
}

// ---------------------------------------------------------------------------
// Kernel 5: fused logits + softmax. 64-row blocks x 256 threads (4 waves),
// grid (32,4) = 128 blocks. Fast tanh via __expf.
// ---------------------------------------------------------------------------
__global__ __launch_bounds__(256) void logits_softmax_kernel(
    const __hip_bfloat16* __restrict__ att, const __hip_bfloat16* __restrict__ em,
    const float* __restrict__ be, const u64* __restrict__ maskbits,
    float* __restrict__ out)
{
    __shared__ short Asl[4][64 * 32];    // 16 KB
    __shared__ short Bsl[4][208 * 32];   // 53 KB
    __shared__ u64 sm[64][4];
    __shared__ float sbe[208];
    int b = blockIdx.x, m0 = blockIdx.y * 64;
    int t = threadIdx.x, wave = t >> 6, lane = t & 63;
    int lrow = lane >> 2, cg = lane & 3, ss = (lane >> 3) & 3, gq = (cg - ss) & 3;
    int rrow = lane & 15, quad = lane >> 4, srd = (rrow >> 1) & 3;

    const short* Aa = (const short*)att + ((size_t)b * Rc + m0) * 128;
    const short* Ben = (const short*)em + (size_t)b * Nc * 128;

    #pragma unroll
    for (int kc = 0; kc < 4; ++kc)
        GLOAD_LDS16(Aa + (size_t)(wave * 16 + lrow) * 128 + kc * 32 + gq * 8,
                    &Asl[kc][(wave * 16) * 32]);
    for (int cch = wave; cch < 13; cch += 4)
        #pragma unroll
        for (int kc = 0; kc < 4; ++kc)
            GLOAD_LDS16(Ben + (size_t)(cch * 16 + lrow) * 128 + kc * 32 + gq * 8,
                        &Bsl[kc][(cch * 16) * 32]);
    {
        int r = t >> 2, w = t & 3;   // 256 threads = 64 rows x 4 words
        sm[r][w] = (m0 + r < Rc) ? maskbits[((size_t)b * Rc + m0 + r) * 4 + w] : 0ull;
    }
    if (t < 208) sbe[t] = (t < Nc) ? be[(size_t)b * Nc + t] : 0.f;
    __syncthreads();

    short8 afr[4];
    #pragma unroll
    for (int kc = 0; kc < 4; ++kc)
        afr[kc] = *(const short8*)&Asl[kc][(wave * 16 + rrow) * 32 + ((quad + srd) & 3) * 8];

    f32x4 acc[13];
    #pragma unroll
    for (int nt = 0; nt < 13; ++nt)
        acc[nt] = (f32x4){0.f, 0.f, 0.f, 0.f};
    #pragma unroll
    for (int nt = 0; nt < 13; ++nt)
        #pragma unroll
        for (int kc = 0; kc < 4; ++kc) {
            short8 bfr = *(const short8*)
                &Bsl[kc][(nt * 16 + rrow) * 32 + ((quad + srd) & 3) * 8];
            acc[nt] = __builtin_amdgcn_mfma_f32_16x16x32_bf16(afr[kc], bfr, acc[nt], 0, 0, 0);
        }

    const float scale = 0.08838834764831843f;  // 1/sqrt(128)
    #pragma unroll
    for (int i = 0; i < 4; ++i) {
        int rloc = wave * 16 + quad * 4 + i;
        int r = m0 + rloc;
        u64 w0 = sm[rloc][0], w1 = sm[rloc][1], w2 = sm[rloc][2], w3 = sm[rloc][3];
        float vals[13];
        float mx = -INFINITY;
        #pragma unroll
        for (int nt = 0; nt < 13; ++nt) {
            u64 w = (nt < 4) ? w0 : (nt < 8) ? w1 : (nt < 12) ? w2 : w3;
            int sh = ((nt & 3) << 4) + rrow;
            float lg = -INFINITY;
            if ((w >> sh) & 1ull) {
                float y = (acc[nt][i] + sbe[nt * 16 + rrow]) * scale;
                // tanh(y) = 1 - 2/(e^{2y}+1); exact limits at +-inf, no NaN.
                float e = __expf(2.f * y);
                lg = 10.f * (1.f - 2.f / (e + 1.f));
            }
            vals[nt] = lg;
            mx = fmaxf(mx, lg);
        }
        mx = fmaxf(mx, __shfl_xor(mx, 1));
        mx = fmaxf(mx, __shfl_xor(mx, 2));
        mx = fmaxf(mx, __shfl_xor(mx, 4));
        mx = fmaxf(mx, __shfl_xor(mx, 8));
        float l = 0.f;
        #pragma unroll
        for (int nt = 0; nt < 13; ++nt) {
            float p = (vals[nt] == -INFINITY) ? 0.f : __expf(vals[nt] - mx);
            vals[nt] = p;
            l += p;
        }
        l += __shfl_xor(l, 1);
        l += __shfl_xor(l, 2);
        l += __shfl_xor(l, 4);
        l += __shfl_xor(l, 8);
        float inv = (l > 0.f) ? 1.f / l : 0.f;
        if (r < Rc) {
            #pragma unroll
            for (int nt = 0; nt < 13; ++nt) {
                int n = nt * 16 + rrow;
                if (n < Nc)
                    out[((size_t)b * Rc + r) * Nc + n] = vals[nt] * inv;
            }
        }
    }
}

// ---------------------------------------------------------------------------
extern "C" void kernel_launch(void* const* d_in, const int* in_sizes, int n_in,
                              void* d_out, int out_size, void* d_ws, size_t ws_size,
                              hipStream_t stream)
{
    const float* enc  = (const float*)d_in[0];
    const float* dist = (const float*)d_in[1];
    const float* mask = (const float*)d_in[2];
    const int*   cur  = (const int*)d_in[3];
    const float* Wq   = (const float*)d_in[4];
    const float* Wk   = (const float*)d_in[5];
    const float* Wv   = (const float*)d_in[6];
    const float* Wmhc = (const float*)d_in[7];
    const float* bmhc = (const float*)d_in[8];
    const float* W1   = (const float*)d_in[9];
    const float* b1   = (const float*)d_in[10];
    const float* W2   = (const float*)d_in[11];
    const float* b2   = (const float*)d_in[12];
    float* out = (float*)d_out;

    char* ws = (char*)d_ws;
    size_t off = 0;
    auto alloc = [&](size_t bytes) { char* p = ws + off; off += (bytes + 255) & ~(size_t)255; return p; };
    __hip_bfloat16* W1t  = (__hip_bfloat16*)alloc((size_t)640 * 1280 * 2);
    __hip_bfloat16* Wkvt = (__hip_bfloat16*)alloc((size_t)256 * 128 * 2);
    __hip_bfloat16* Wmb  = (__hip_bfloat16*)alloc((size_t)128 * 128 * 2);
    __hip_bfloat16* Wcat = (__hip_bfloat16*)alloc((size_t)128 * 768 * 2);
    float* bq = (float*)alloc((size_t)128 * 4);
    // encb: rows [0, Bc*Nc) = enc bf16; rows [Bc*Nc, Bc*Nc+BRc) = mean rows
    __hip_bfloat16* encb = (__hip_bfloat16*)alloc((size_t)(Bc * Nc + BRc + 64) * Dc * 2);
    unsigned* aoff = (unsigned*)alloc((size_t)BRc * 16 * 4);
    __hip_bfloat16* hq   = (__hip_bfloat16*)alloc((size_t)BRc * 768 * 2);
    __hip_bfloat16* q    = (__hip_bfloat16*)alloc((size_t)BRc * 128 * 2);
    __hip_bfloat16* kvf  = (__hip_bfloat16*)alloc((size_t)Bc * Nc * 256 * 2);
    __hip_bfloat16* att  = (__hip_bfloat16*)alloc((size_t)(BRc + 64) * 128 * 2);
    __hip_bfloat16* em   = (__hip_bfloat16*)alloc((size_t)(Bc * Nc + 64) * 128 * 2);
    float* be = (float*)alloc((size_t)Bc * Nc * 4);
    u64* maskbits = (u64*)alloc((size_t)BRc * 4 * 8);

    // 1) prep + kNN (independent roles, one launch, 2530 blocks)
    prep_knn_kernel<<<2530, 256, 0, stream>>>(
        W1, W2, Wq, Wmhc, Wk, Wv, b2, enc, dist, mask, cur,
        W1t, Wkvt, Wmb, Wcat, bq, encb, aoff, hq, maskbits);
    // 2) gemm1 (2-phase dbuf BK=64) + kvf + em + be (one launch, 1625 blocks)
    fused_gemms_kernel<<<1625, 256, 0, stream>>>(
        encb, aoff, W1t, b1, Wkvt, Wmb, bmhc, enc, hq, kvf, em, be);
    // 3) q = hq @ Wcat^T + bq  (2-phase dbuf BK=64, 200 blocks)
    qgemm_kernel<<<dim3(2, BRc / 64), 256, 0, stream>>>(hq, Wcat, bq, q);
    // 4) MFMA flash attention (split row-tile halves: 512 blocks)
    attn_mfma_kernel<<<dim3(Bc * Hc, 2), 256, 0, stream>>>(q, kvf, maskbits, att);
    // 5) fused logits + softmax (64-row blocks x 4 waves, grid (32,4) = 128 blocks)
    logits_softmax_kernel<<<dim3(Bc, 4), 256, 0, stream>>>(att, em, be, maskbits, out);
}